// Round 1
// baseline (1210.838 us; speedup 1.0000x reference)
//
#include <hip/hip_runtime.h>

#define NN 100000
#define NE 1600000
#define NG 4096
#define HD 128
#define EPSV 1e-5f
#define NB_STAT 256
#define NB_SCAN 391   // ceil(100000/256)

// ---------------- CSR build ----------------

__global__ void k_zero_i32(int* p, int n) {
    int i = blockIdx.x * blockDim.x + threadIdx.x;
    if (i < n) p[i] = 0;
}

__global__ void k_deg(const int* __restrict__ ei, int* __restrict__ degi) {
    int e = blockIdx.x * blockDim.x + threadIdx.x;
    if (e < NE) atomicAdd(&degi[ei[NE + e]], 1);
}

__global__ void k_dinv(const int* __restrict__ degi, float* __restrict__ dinv) {
    int n = blockIdx.x * blockDim.x + threadIdx.x;
    if (n < NN) dinv[n] = rsqrtf((float)(degi[n] + 1));  // +1 self loop; always >=1
}

__global__ void k_scan1(const int* __restrict__ degi, int* __restrict__ rp, int* __restrict__ bsum) {
    __shared__ int s[256];
    int t = threadIdx.x;
    int i = blockIdx.x * 256 + t;
    int v = (i < NN) ? (degi[i] + 1) : 0;
    s[t] = v;
    __syncthreads();
    for (int off = 1; off < 256; off <<= 1) {
        int x = (t >= off) ? s[t - off] : 0;
        __syncthreads();
        s[t] += x;
        __syncthreads();
    }
    if (i < NN) rp[i] = s[t] - v;        // block-local exclusive
    if (t == 255) bsum[blockIdx.x] = s[255];
}

__global__ void k_scan2(const int* __restrict__ bsum, int* __restrict__ bsumex) {
    __shared__ int s[512];
    int t = threadIdx.x;
    int v = (t < NB_SCAN) ? bsum[t] : 0;
    s[t] = v;
    __syncthreads();
    for (int off = 1; off < 512; off <<= 1) {
        int x = (t >= off) ? s[t - off] : 0;
        __syncthreads();
        s[t] += x;
        __syncthreads();
    }
    if (t < NB_SCAN) bsumex[t] = s[t] - v;
    if (t == NB_SCAN) bsumex[NB_SCAN] = s[t];  // total = E + N (pad lanes add 0)
}

__global__ void k_scan3(int* __restrict__ rp, const int* __restrict__ bsumex, int* __restrict__ cur) {
    int i = blockIdx.x * blockDim.x + threadIdx.x;
    if (i < NN) {
        int v = rp[i] + bsumex[i >> 8];
        rp[i] = v;
        cur[i] = v;
    } else if (i == NN) {
        rp[NN] = bsumex[NB_SCAN];
    }
}

__global__ void k_scatter(const int* __restrict__ ei, const float* __restrict__ dinv,
                          int* __restrict__ cur, int* __restrict__ col, float* __restrict__ wgt) {
    int t = blockIdx.x * blockDim.x + threadIdx.x;
    if (t < NE) {
        int s = ei[t], d = ei[NE + t];
        int pos = atomicAdd(&cur[d], 1);
        col[pos] = s;
        wgt[pos] = dinv[s] * dinv[d];
    } else if (t < NE + NN) {
        int n = t - NE;
        int pos = atomicAdd(&cur[n], 1);
        col[pos] = n;
        wgt[pos] = dinv[n] * dinv[n];
    }
}

// ---------------- GCN layers ----------------

// layer 0: [N,9] @ [9,128]; wave per node, lane -> 2 channels
__global__ void k_mm9(const float* __restrict__ x, const float* __restrict__ w0, float* __restrict__ hout) {
    int t = blockIdx.x * blockDim.x + threadIdx.x;
    int n = t >> 6, l = t & 63;
    if (n >= NN) return;
    int c = 2 * l;
    float2 acc = make_float2(0.f, 0.f);
#pragma unroll
    for (int k = 0; k < 9; ++k) {
        float a = x[n * 9 + k];
        float2 wv = *(const float2*)&w0[k * HD + c];
        acc.x += a * wv.x;
        acc.y += a * wv.y;
    }
    *(float2*)&hout[n * HD + c] = acc;
}

// [N,128] @ [128,128]; wave handles 8 nodes, lane -> 2 channels. W from global (L1/L2 resident).
__global__ __launch_bounds__(256) void k_mm128(const float* __restrict__ hin, const float* __restrict__ W,
                                               float* __restrict__ hout) {
    __shared__ __align__(16) float xs[4][8][HD];
    int t = threadIdx.x;
    int w = t >> 6, l = t & 63, c = 2 * l;
    int wid = blockIdx.x * 4 + w;
    int nw = gridDim.x * 4;
    for (int base = wid * 8; base < NN; base += nw * 8) {
#pragma unroll
        for (int j = 0; j < 8; ++j) {
            int n = base + j;
            float2 v = make_float2(0.f, 0.f);
            if (n < NN) v = *(const float2*)&hin[n * HD + c];
            *(float2*)&xs[w][j][c] = v;
        }
        float2 acc[8];
#pragma unroll
        for (int j = 0; j < 8; ++j) acc[j] = make_float2(0.f, 0.f);
        for (int k4 = 0; k4 < HD / 4; ++k4) {
            float4 a[8];
#pragma unroll
            for (int j = 0; j < 8; ++j) a[j] = *(const float4*)&xs[w][j][k4 * 4];
#pragma unroll
            for (int kk = 0; kk < 4; ++kk) {
                float2 wv = *(const float2*)&W[(k4 * 4 + kk) * HD + c];
#pragma unroll
                for (int j = 0; j < 8; ++j) {
                    float av = ((const float*)&a[j])[kk];
                    acc[j].x += av * wv.x;
                    acc[j].y += av * wv.y;
                }
            }
        }
#pragma unroll
        for (int j = 0; j < 8; ++j) {
            int n = base + j;
            if (n < NN) *(float2*)&hout[n * HD + c] = acc[j];
        }
    }
}

// CSR gather: wave per node
__global__ void k_agg(const float* __restrict__ hin, float* __restrict__ hout,
                      const int* __restrict__ rp, const int* __restrict__ col,
                      const float* __restrict__ wgt) {
    int l = threadIdx.x & 63;
    int wid = blockIdx.x * (blockDim.x >> 6) + (threadIdx.x >> 6);
    int nw = gridDim.x * (blockDim.x >> 6);
    int c = 2 * l;
    for (int n = wid; n < NN; n += nw) {
        int s = rp[n], e = rp[n + 1];
        float2 acc = make_float2(0.f, 0.f);
        for (int i = s; i < e; ++i) {
            int cc = col[i];
            float ww = wgt[i];
            float2 v = *(const float2*)&hin[cc * HD + c];
            acc.x += ww * v.x;
            acc.y += ww * v.y;
        }
        *(float2*)&hout[n * HD + c] = acc;
    }
}

// BN stats stage 1: per-block double partial sum/sumsq per channel
__global__ void k_stats1(const float* __restrict__ h, double* __restrict__ ps, double* __restrict__ ps2) {
    __shared__ double sd[256], sd2[256];
    int b = blockIdx.x, t = threadIdx.x;
    int c = t & 127, half = t >> 7;
    const int chunk = (NN + NB_STAT - 1) / NB_STAT;  // 391
    int r0 = b * chunk;
    int r1 = min(NN, r0 + chunk);
    double s = 0.0, s2 = 0.0;
    for (int r = r0 + half; r < r1; r += 2) {
        float v = h[r * HD + c];
        s += v;
        s2 += (double)v * v;
    }
    sd[t] = s;
    sd2[t] = s2;
    __syncthreads();
    if (half == 0) {
        ps[b * 128 + c] = sd[t] + sd[t + 128];
        ps2[b * 128 + c] = sd2[t] + sd2[t + 128];
    }
}

__global__ void k_stats2(const double* __restrict__ ps, const double* __restrict__ ps2,
                         const float* __restrict__ g, const float* __restrict__ be,
                         float* __restrict__ scale, float* __restrict__ shift) {
    int c = threadIdx.x;  // 128 threads
    double s = 0.0, s2 = 0.0;
    for (int b = 0; b < NB_STAT; ++b) {
        s += ps[b * 128 + c];
        s2 += ps2[b * 128 + c];
    }
    double mu = s / NN;
    double var = s2 / NN - mu * mu;
    float sc = g[c] * rsqrtf((float)var + EPSV);
    scale[c] = sc;
    shift[c] = be[c] - (float)mu * sc;
}

__global__ void k_bnrelu(float* __restrict__ h, const float* __restrict__ scale,
                         const float* __restrict__ shift) {
    int i = blockIdx.x * blockDim.x + threadIdx.x;  // float4 index; grid sized exactly N*32
    float4 v = ((const float4*)h)[i];
    int cq = i & 31;
    float4 sc = ((const float4*)scale)[cq];
    float4 sh = ((const float4*)shift)[cq];
    v.x = fmaxf(v.x * sc.x + sh.x, 0.f);
    v.y = fmaxf(v.y * sc.y + sh.y, 0.f);
    v.z = fmaxf(v.z * sc.z + sh.z, 0.f);
    v.w = fmaxf(v.w * sc.w + sh.w, 0.f);
    ((float4*)h)[i] = v;
}

// ---------------- pooling + MLP ----------------

__global__ void k_pool(const float* __restrict__ h, const int* __restrict__ batch, float* __restrict__ xg) {
    int l = threadIdx.x & 63;
    int g = blockIdx.x * (blockDim.x >> 6) + (threadIdx.x >> 6);
    if (g >= NG) return;
    int lo = 0, hi = NN;
    while (lo < hi) { int m = (lo + hi) >> 1; if (batch[m] < g) lo = m + 1; else hi = m; }
    int s = lo;
    hi = NN;
    while (lo < hi) { int m = (lo + hi) >> 1; if (batch[m] < g + 1) lo = m + 1; else hi = m; }
    int e = lo;
    int c = 2 * l;
    float2 sum = make_float2(0.f, 0.f), mx = make_float2(-3e38f, -3e38f);
    for (int r = s; r < e; ++r) {
        float2 v = *(const float2*)&h[r * HD + c];
        sum.x += v.x; sum.y += v.y;
        mx.x = fmaxf(mx.x, v.x); mx.y = fmaxf(mx.y, v.y);
    }
    float2 mean = make_float2(0.f, 0.f), mxo = make_float2(0.f, 0.f);
    if (e > s) {
        float cnt = (float)(e - s);
        mean.x = sum.x / cnt; mean.y = sum.y / cnt;
        mxo = mx;
    }
    *(float2*)&xg[g * 256 + c] = mean;
    *(float2*)&xg[g * 256 + 128 + c] = mxo;
}

#define GPB 8
__global__ __launch_bounds__(256) void k_mlp(const float* __restrict__ xg,
                                             const float* __restrict__ m0w, const float* __restrict__ m0b,
                                             const float* __restrict__ m1w, const float* __restrict__ m1b,
                                             const float* __restrict__ m2w, const float* __restrict__ m2b,
                                             float* __restrict__ out) {
    __shared__ float xs[GPB][256];
    __shared__ float h1[GPB][256];
    __shared__ float h2[GPB][64];
    int t = threadIdx.x;
    int g0 = blockIdx.x * GPB;
#pragma unroll
    for (int j = 0; j < GPB; ++j) xs[j][t] = xg[(g0 + j) * 256 + t];
    __syncthreads();
    float acc[GPB];
#pragma unroll
    for (int j = 0; j < GPB; ++j) acc[j] = m0b[t];
    for (int i = 0; i < 256; ++i) {
        float wv = m0w[i * 256 + t];
#pragma unroll
        for (int j = 0; j < GPB; ++j) acc[j] += xs[j][i] * wv;
    }
#pragma unroll
    for (int j = 0; j < GPB; ++j) h1[j][t] = fmaxf(acc[j], 0.f);
    __syncthreads();
    if (t < 64) {
        float a2[GPB];
#pragma unroll
        for (int j = 0; j < GPB; ++j) a2[j] = m1b[t];
        for (int i = 0; i < 256; ++i) {
            float wv = m1w[i * 64 + t];
#pragma unroll
            for (int j = 0; j < GPB; ++j) a2[j] += h1[j][i] * wv;
        }
#pragma unroll
        for (int j = 0; j < GPB; ++j) h2[j][t] = fmaxf(a2[j], 0.f);
    }
    __syncthreads();
    if (t < 64) {
#pragma unroll
        for (int j = 0; j < GPB; ++j) {
            float v = h2[j][t] * m2w[t];
            for (int off = 32; off; off >>= 1) v += __shfl_down(v, off);
            if (t == 0) out[g0 + j] = v + m2b[0];
        }
    }
}

// ---------------- launch ----------------

extern "C" void kernel_launch(void* const* d_in, const int* in_sizes, int n_in,
                              void* d_out, int out_size, void* d_ws, size_t ws_size,
                              hipStream_t stream) {
    const float* x    = (const float*)d_in[0];
    const int*   ei   = (const int*)d_in[1];
    const int*   batch= (const int*)d_in[2];
    const float* w0   = (const float*)d_in[3];
    const float* w12  = (const float*)d_in[4];
    // d_in[5] = cb : mathematically cancelled by BN (mean-subtraction), unused
    const float* bn_g = (const float*)d_in[6];
    const float* bn_b = (const float*)d_in[7];
    const float* m0w  = (const float*)d_in[8];
    const float* m0b  = (const float*)d_in[9];
    const float* m1w  = (const float*)d_in[10];
    const float* m1b  = (const float*)d_in[11];
    const float* m2w  = (const float*)d_in[12];
    const float* m2b  = (const float*)d_in[13];
    float* out = (float*)d_out;

    char* p = (char*)d_ws;
    auto alloc = [&](size_t bytes) {
        void* r = (void*)p;
        p += (bytes + 255) & ~(size_t)255;
        return r;
    };
    float*  hbuf0  = (float*)alloc((size_t)NN * HD * 4);
    float*  hbuf1  = (float*)alloc((size_t)NN * HD * 4);
    int*    degi   = (int*)alloc((size_t)NN * 4);
    float*  dinv   = (float*)alloc((size_t)NN * 4);
    int*    rp     = (int*)alloc((size_t)(NN + 1) * 4);
    int*    cur    = (int*)alloc((size_t)NN * 4);
    int*    col    = (int*)alloc((size_t)(NE + NN) * 4);
    float*  wgt    = (float*)alloc((size_t)(NE + NN) * 4);
    int*    bsum   = (int*)alloc(512 * 4);
    int*    bsumex = (int*)alloc(512 * 4);
    double* ps     = (double*)alloc((size_t)NB_STAT * 128 * 8);
    double* ps2    = (double*)alloc((size_t)NB_STAT * 128 * 8);
    float*  scale  = (float*)alloc(128 * 4);
    float*  shift  = (float*)alloc(128 * 4);
    float*  xg     = (float*)alloc((size_t)NG * 256 * 4);

    // ---- CSR build (per call; deterministic work) ----
    k_zero_i32<<<(NN + 255) / 256, 256, 0, stream>>>(degi, NN);
    k_deg<<<(NE + 255) / 256, 256, 0, stream>>>(ei, degi);
    k_dinv<<<(NN + 255) / 256, 256, 0, stream>>>(degi, dinv);
    k_scan1<<<NB_SCAN, 256, 0, stream>>>(degi, rp, bsum);
    k_scan2<<<1, 512, 0, stream>>>(bsum, bsumex);
    k_scan3<<<NB_SCAN + 1, 256, 0, stream>>>(rp, bsumex, cur);
    k_scatter<<<(NE + NN + 255) / 256, 256, 0, stream>>>(ei, dinv, cur, col, wgt);

    // ---- layer 0 ----
    k_mm9<<<25000, 256, 0, stream>>>(x, w0, hbuf0);
    k_agg<<<4096, 256, 0, stream>>>(hbuf0, hbuf1, rp, col, wgt);
    k_stats1<<<NB_STAT, 256, 0, stream>>>(hbuf1, ps, ps2);
    k_stats2<<<1, 128, 0, stream>>>(ps, ps2, bn_g + 0, bn_b + 0, scale, shift);
    k_bnrelu<<<12500, 256, 0, stream>>>(hbuf1, scale, shift);

    // ---- layer 1 ----
    k_mm128<<<1024, 256, 0, stream>>>(hbuf1, w12, hbuf0);
    k_agg<<<4096, 256, 0, stream>>>(hbuf0, hbuf1, rp, col, wgt);
    k_stats1<<<NB_STAT, 256, 0, stream>>>(hbuf1, ps, ps2);
    k_stats2<<<1, 128, 0, stream>>>(ps, ps2, bn_g + 128, bn_b + 128, scale, shift);
    k_bnrelu<<<12500, 256, 0, stream>>>(hbuf1, scale, shift);

    // ---- layer 2 ----
    k_mm128<<<1024, 256, 0, stream>>>(hbuf1, w12 + 128 * 128, hbuf0);
    k_agg<<<4096, 256, 0, stream>>>(hbuf0, hbuf1, rp, col, wgt);
    k_stats1<<<NB_STAT, 256, 0, stream>>>(hbuf1, ps, ps2);
    k_stats2<<<1, 128, 0, stream>>>(ps, ps2, bn_g + 256, bn_b + 256, scale, shift);
    k_bnrelu<<<12500, 256, 0, stream>>>(hbuf1, scale, shift);

    // ---- pool + MLP ----
    k_pool<<<NG / 4, 256, 0, stream>>>(hbuf1, batch, xg);
    k_mlp<<<NG / GPB, 256, 0, stream>>>(xg, m0w, m0b, m1w, m1b, m2w, m2b, out);
}

// Round 2
// 840.923 us; speedup vs baseline: 1.4399x; 1.4399x over previous
//
#include <hip/hip_runtime.h>
#include <hip/hip_fp16.h>

#define NN 100000
#define NE 1600000
#define NG 4096
#define HD 128
#define EPSV 1e-5f
#define NB_STAT 256
#define NB_SCAN 391   // ceil(100000/256)

// ---------------- CSR build ----------------

__global__ void k_zero_i32(int* p, int n) {
    int i = blockIdx.x * blockDim.x + threadIdx.x;
    if (i < n) p[i] = 0;
}

__global__ void k_deg(const int* __restrict__ ei, int* __restrict__ degi) {
    int e = blockIdx.x * blockDim.x + threadIdx.x;
    if (e < NE) atomicAdd(&degi[ei[NE + e]], 1);
}

__global__ void k_dinv(const int* __restrict__ degi, float* __restrict__ dinv) {
    int n = blockIdx.x * blockDim.x + threadIdx.x;
    if (n < NN) dinv[n] = rsqrtf((float)(degi[n] + 1));  // +1 self loop
}

__global__ void k_scan1(const int* __restrict__ degi, int* __restrict__ rp, int* __restrict__ bsum) {
    __shared__ int s[256];
    int t = threadIdx.x;
    int i = blockIdx.x * 256 + t;
    int v = (i < NN) ? (degi[i] + 1) : 0;
    s[t] = v;
    __syncthreads();
    for (int off = 1; off < 256; off <<= 1) {
        int x = (t >= off) ? s[t - off] : 0;
        __syncthreads();
        s[t] += x;
        __syncthreads();
    }
    if (i < NN) rp[i] = s[t] - v;
    if (t == 255) bsum[blockIdx.x] = s[255];
}

__global__ void k_scan2(const int* __restrict__ bsum, int* __restrict__ bsumex) {
    __shared__ int s[512];
    int t = threadIdx.x;
    int v = (t < NB_SCAN) ? bsum[t] : 0;
    s[t] = v;
    __syncthreads();
    for (int off = 1; off < 512; off <<= 1) {
        int x = (t >= off) ? s[t - off] : 0;
        __syncthreads();
        s[t] += x;
        __syncthreads();
    }
    if (t < NB_SCAN) bsumex[t] = s[t] - v;
    if (t == NB_SCAN) bsumex[NB_SCAN] = s[t];
}

__global__ void k_scan3(int* __restrict__ rp, const int* __restrict__ bsumex, int* __restrict__ cur) {
    int i = blockIdx.x * blockDim.x + threadIdx.x;
    if (i < NN) {
        int v = rp[i] + bsumex[i >> 8];
        rp[i] = v;
        cur[i] = v;
    } else if (i == NN) {
        rp[NN] = bsumex[NB_SCAN];
    }
}

__global__ void k_scatter(const int* __restrict__ ei, const float* __restrict__ dinv,
                          int* __restrict__ cur, int* __restrict__ col, float* __restrict__ wgt) {
    int t = blockIdx.x * blockDim.x + threadIdx.x;
    if (t < NE) {
        int s = ei[t], d = ei[NE + t];
        int pos = atomicAdd(&cur[d], 1);
        col[pos] = s;
        wgt[pos] = dinv[s] * dinv[d];
    } else if (t < NE + NN) {
        int n = t - NE;
        int pos = atomicAdd(&cur[n], 1);
        col[pos] = n;
        wgt[pos] = dinv[n] * dinv[n];
    }
}

// ---------------- layer 0: aggregate x first (A·X)·W0 == A·(X·W0) ----------------

// pad x [N,9] -> x16 [N,16] (one 64B line per row)
__global__ void k_padx(const float* __restrict__ x, float* __restrict__ x16) {
    int i = blockIdx.x * blockDim.x + threadIdx.x;   // N*16
    int n = i >> 4, c = i & 15;
    x16[i] = (c < 9) ? x[n * 9 + c] : 0.f;
}

// 4 lanes per node, lane holds float4; one full cache line per neighbor
__global__ void k_aggx(const float* __restrict__ x16, float* __restrict__ aggx,
                       const int* __restrict__ rp, const int* __restrict__ col,
                       const float* __restrict__ wgt) {
    int t = blockIdx.x * blockDim.x + threadIdx.x;
    int n = t >> 2, sub = (t & 3) * 4;
    if (n >= NN) return;
    int s = rp[n], e = rp[n + 1];
    float4 acc = make_float4(0.f, 0.f, 0.f, 0.f);
    for (int i = s; i < e; ++i) {
        int cc = col[i];
        float w = wgt[i];
        float4 v = *(const float4*)&x16[cc * 16 + sub];
        acc.x += w * v.x; acc.y += w * v.y; acc.z += w * v.z; acc.w += w * v.w;
    }
    *(float4*)&aggx[n * 16 + sub] = acc;
}

// aggx [N,16(9)] @ w0 [9,128] -> g0 [N,128] fp32 (pre-BN); wave per node
__global__ void k_mm9(const float* __restrict__ aggx, const float* __restrict__ w0,
                      float* __restrict__ gout) {
    int t = blockIdx.x * blockDim.x + threadIdx.x;
    int n = t >> 6, l = t & 63;
    if (n >= NN) return;
    int c = 2 * l;
    float2 acc = make_float2(0.f, 0.f);
#pragma unroll
    for (int k = 0; k < 9; ++k) {
        float a = aggx[n * 16 + k];
        float2 wv = *(const float2*)&w0[k * HD + c];
        acc.x += a * wv.x;
        acc.y += a * wv.y;
    }
    *(float2*)&gout[n * HD + c] = acc;
}

// ---------------- fused BN+ReLU matmul -> fp16 ----------------

// hout[n] = relu(g[n]*scale+shift) @ W, written fp16
__global__ __launch_bounds__(256) void k_mm128_fused(const float* __restrict__ hin,
        const float* __restrict__ scale, const float* __restrict__ shift,
        const float* __restrict__ W, __half* __restrict__ hout) {
    __shared__ __align__(16) float xs[4][8][HD];
    int t = threadIdx.x;
    int w = t >> 6, l = t & 63, c = 2 * l;
    float2 sc = make_float2(scale[c], scale[c + 1]);
    float2 sh = make_float2(shift[c], shift[c + 1]);
    int wid = blockIdx.x * 4 + w;
    int nw = gridDim.x * 4;
    for (int base = wid * 8; base < NN; base += nw * 8) {
#pragma unroll
        for (int j = 0; j < 8; ++j) {
            int n = base + j;
            float2 v = make_float2(0.f, 0.f);
            if (n < NN) {
                v = *(const float2*)&hin[n * HD + c];
                v.x = fmaxf(v.x * sc.x + sh.x, 0.f);
                v.y = fmaxf(v.y * sc.y + sh.y, 0.f);
            }
            *(float2*)&xs[w][j][c] = v;
        }
        float2 acc[8];
#pragma unroll
        for (int j = 0; j < 8; ++j) acc[j] = make_float2(0.f, 0.f);
        for (int k4 = 0; k4 < HD / 4; ++k4) {
            float4 a[8];
#pragma unroll
            for (int j = 0; j < 8; ++j) a[j] = *(const float4*)&xs[w][j][k4 * 4];
#pragma unroll
            for (int kk = 0; kk < 4; ++kk) {
                float2 wv = *(const float2*)&W[(k4 * 4 + kk) * HD + c];
#pragma unroll
                for (int j = 0; j < 8; ++j) {
                    float av = ((const float*)&a[j])[kk];
                    acc[j].x += av * wv.x;
                    acc[j].y += av * wv.y;
                }
            }
        }
#pragma unroll
        for (int j = 0; j < 8; ++j) {
            int n = base + j;
            if (n < NN) *(__half2*)&hout[n * HD + c] = __floats2half2_rn(acc[j].x, acc[j].y);
        }
    }
}

// CSR gather on fp16 rows -> fp32 out; wave per node, 2-unrolled
__global__ void k_agg_h(const __half* __restrict__ hh, float* __restrict__ gout,
                        const int* __restrict__ rp, const int* __restrict__ col,
                        const float* __restrict__ wgt) {
    int l = threadIdx.x & 63;
    int wid = blockIdx.x * (blockDim.x >> 6) + (threadIdx.x >> 6);
    int nw = gridDim.x * (blockDim.x >> 6);
    int c = 2 * l;
    for (int n = wid; n < NN; n += nw) {
        int s = rp[n], e = rp[n + 1];
        float2 acc = make_float2(0.f, 0.f);
        int i = s;
        for (; i + 1 < e; i += 2) {
            int c0 = col[i], c1 = col[i + 1];
            float w0 = wgt[i], w1 = wgt[i + 1];
            __half2 v0 = *(const __half2*)&hh[c0 * HD + c];
            __half2 v1 = *(const __half2*)&hh[c1 * HD + c];
            float2 f0 = __half22float2(v0);
            float2 f1 = __half22float2(v1);
            acc.x += w0 * f0.x + w1 * f1.x;
            acc.y += w0 * f0.y + w1 * f1.y;
        }
        if (i < e) {
            float w0 = wgt[i];
            float2 f0 = __half22float2(*(const __half2*)&hh[col[i] * HD + c]);
            acc.x += w0 * f0.x;
            acc.y += w0 * f0.y;
        }
        *(float2*)&gout[n * HD + c] = acc;
    }
}

// ---------------- BN stats (on fp32 pre-BN agg) ----------------

__global__ void k_stats1(const float* __restrict__ h, double* __restrict__ ps, double* __restrict__ ps2) {
    __shared__ double sd[256], sd2[256];
    int b = blockIdx.x, t = threadIdx.x;
    int c = t & 127, half = t >> 7;
    const int chunk = (NN + NB_STAT - 1) / NB_STAT;  // 391
    int r0 = b * chunk;
    int r1 = min(NN, r0 + chunk);
    double s = 0.0, s2 = 0.0;
    for (int r = r0 + half; r < r1; r += 2) {
        float v = h[r * HD + c];
        s += v;
        s2 += (double)v * v;
    }
    sd[t] = s;
    sd2[t] = s2;
    __syncthreads();
    if (half == 0) {
        ps[b * 128 + c] = sd[t] + sd[t + 128];
        ps2[b * 128 + c] = sd2[t] + sd2[t + 128];
    }
}

__global__ void k_stats2(const double* __restrict__ ps, const double* __restrict__ ps2,
                         const float* __restrict__ g, const float* __restrict__ be,
                         float* __restrict__ scale, float* __restrict__ shift) {
    int c = threadIdx.x;  // 128 threads
    double s = 0.0, s2 = 0.0;
    for (int b = 0; b < NB_STAT; ++b) {
        s += ps[b * 128 + c];
        s2 += ps2[b * 128 + c];
    }
    double mu = s / NN;
    double var = s2 / NN - mu * mu;
    float sc = g[c] * rsqrtf((float)var + EPSV);
    scale[c] = sc;
    shift[c] = be[c] - (float)mu * sc;
}

// ---------------- pooling (fused final BN+ReLU) + MLP ----------------

__global__ void k_pool_fused(const float* __restrict__ h, const float* __restrict__ scale,
                             const float* __restrict__ shift, const int* __restrict__ batch,
                             float* __restrict__ xg) {
    int l = threadIdx.x & 63;
    int g = blockIdx.x * (blockDim.x >> 6) + (threadIdx.x >> 6);
    if (g >= NG) return;
    int c = 2 * l;
    float2 sc = make_float2(scale[c], scale[c + 1]);
    float2 sh = make_float2(shift[c], shift[c + 1]);
    int lo = 0, hi = NN;
    while (lo < hi) { int m = (lo + hi) >> 1; if (batch[m] < g) lo = m + 1; else hi = m; }
    int s = lo;
    hi = NN;
    while (lo < hi) { int m = (lo + hi) >> 1; if (batch[m] < g + 1) lo = m + 1; else hi = m; }
    int e = lo;
    float2 sum = make_float2(0.f, 0.f), mx = make_float2(-3e38f, -3e38f);
    for (int r = s; r < e; ++r) {
        float2 v = *(const float2*)&h[r * HD + c];
        v.x = fmaxf(v.x * sc.x + sh.x, 0.f);
        v.y = fmaxf(v.y * sc.y + sh.y, 0.f);
        sum.x += v.x; sum.y += v.y;
        mx.x = fmaxf(mx.x, v.x); mx.y = fmaxf(mx.y, v.y);
    }
    float2 mean = make_float2(0.f, 0.f), mxo = make_float2(0.f, 0.f);
    if (e > s) {
        float cnt = (float)(e - s);
        mean.x = sum.x / cnt; mean.y = sum.y / cnt;
        mxo = mx;
    }
    *(float2*)&xg[g * 256 + c] = mean;
    *(float2*)&xg[g * 256 + 128 + c] = mxo;
}

#define GPB 8
__global__ __launch_bounds__(256) void k_mlp(const float* __restrict__ xg,
                                             const float* __restrict__ m0w, const float* __restrict__ m0b,
                                             const float* __restrict__ m1w, const float* __restrict__ m1b,
                                             const float* __restrict__ m2w, const float* __restrict__ m2b,
                                             float* __restrict__ out) {
    __shared__ float xs[GPB][256];
    __shared__ float h1[GPB][256];
    __shared__ float h2[GPB][64];
    int t = threadIdx.x;
    int g0 = blockIdx.x * GPB;
#pragma unroll
    for (int j = 0; j < GPB; ++j) xs[j][t] = xg[(g0 + j) * 256 + t];
    __syncthreads();
    float acc[GPB];
#pragma unroll
    for (int j = 0; j < GPB; ++j) acc[j] = m0b[t];
    for (int i = 0; i < 256; ++i) {
        float wv = m0w[i * 256 + t];
#pragma unroll
        for (int j = 0; j < GPB; ++j) acc[j] += xs[j][i] * wv;
    }
#pragma unroll
    for (int j = 0; j < GPB; ++j) h1[j][t] = fmaxf(acc[j], 0.f);
    __syncthreads();
    if (t < 64) {
        float a2[GPB];
#pragma unroll
        for (int j = 0; j < GPB; ++j) a2[j] = m1b[t];
        for (int i = 0; i < 256; ++i) {
            float wv = m1w[i * 64 + t];
#pragma unroll
            for (int j = 0; j < GPB; ++j) a2[j] += h1[j][i] * wv;
        }
#pragma unroll
        for (int j = 0; j < GPB; ++j) h2[j][t] = fmaxf(a2[j], 0.f);
    }
    __syncthreads();
    if (t < 64) {
#pragma unroll
        for (int j = 0; j < GPB; ++j) {
            float v = h2[j][t] * m2w[t];
            for (int off = 32; off; off >>= 1) v += __shfl_down(v, off);
            if (t == 0) out[g0 + j] = v + m2b[0];
        }
    }
}

// ---------------- launch ----------------

extern "C" void kernel_launch(void* const* d_in, const int* in_sizes, int n_in,
                              void* d_out, int out_size, void* d_ws, size_t ws_size,
                              hipStream_t stream) {
    const float* x    = (const float*)d_in[0];
    const int*   ei   = (const int*)d_in[1];
    const int*   batch= (const int*)d_in[2];
    const float* w0   = (const float*)d_in[3];
    const float* w12  = (const float*)d_in[4];
    // d_in[5] = cb : cancelled by BN mean-subtraction
    const float* bn_g = (const float*)d_in[6];
    const float* bn_b = (const float*)d_in[7];
    const float* m0w  = (const float*)d_in[8];
    const float* m0b  = (const float*)d_in[9];
    const float* m1w  = (const float*)d_in[10];
    const float* m1b  = (const float*)d_in[11];
    const float* m2w  = (const float*)d_in[12];
    const float* m2b  = (const float*)d_in[13];
    float* out = (float*)d_out;

    char* p = (char*)d_ws;
    auto alloc = [&](size_t bytes) {
        void* r = (void*)p;
        p += (bytes + 255) & ~(size_t)255;
        return r;
    };
    float*  buf0   = (float*)alloc((size_t)NN * HD * 4);   // fp32 agg ping
    float*  buf1   = (float*)alloc((size_t)NN * HD * 4);   // fp32 agg pong
    __half* hh     = (__half*)alloc((size_t)NN * HD * 2);  // fp16 h@W for gather
    float*  x16    = (float*)alloc((size_t)NN * 16 * 4);   // padded x; reused as xg later
    float*  aggx   = (float*)alloc((size_t)NN * 16 * 4);
    int*    degi   = (int*)alloc((size_t)NN * 4);
    float*  dinv   = (float*)alloc((size_t)NN * 4);
    int*    rp     = (int*)alloc((size_t)(NN + 1) * 4);
    int*    cur    = (int*)alloc((size_t)NN * 4);
    int*    col    = (int*)alloc((size_t)(NE + NN) * 4);
    float*  wgt    = (float*)alloc((size_t)(NE + NN) * 4);
    int*    bsum   = (int*)alloc(512 * 4);
    int*    bsumex = (int*)alloc(512 * 4);
    double* ps     = (double*)alloc((size_t)NB_STAT * 128 * 8);
    double* ps2    = (double*)alloc((size_t)NB_STAT * 128 * 8);
    float*  scb    = (float*)alloc(3 * 128 * 4);
    float*  shb    = (float*)alloc(3 * 128 * 4);
    float*  xg     = x16;  // alias: x16 dead after k_aggx, xg written much later

    // ---- CSR build ----
    k_zero_i32<<<(NN + 255) / 256, 256, 0, stream>>>(degi, NN);
    k_deg<<<(NE + 255) / 256, 256, 0, stream>>>(ei, degi);
    k_dinv<<<(NN + 255) / 256, 256, 0, stream>>>(degi, dinv);
    k_scan1<<<NB_SCAN, 256, 0, stream>>>(degi, rp, bsum);
    k_scan2<<<1, 512, 0, stream>>>(bsum, bsumex);
    k_scan3<<<NB_SCAN + 1, 256, 0, stream>>>(rp, bsumex, cur);
    k_scatter<<<(NE + NN + 255) / 256, 256, 0, stream>>>(ei, dinv, cur, col, wgt);

    // ---- layer 0: agg(x) @ W0 ----
    k_padx<<<(NN * 16) / 256, 256, 0, stream>>>(x, x16);
    k_aggx<<<(NN * 4 + 255) / 256, 256, 0, stream>>>(x16, aggx, rp, col, wgt);
    k_mm9<<<(NN * 64) / 256, 256, 0, stream>>>(aggx, w0, buf0);
    k_stats1<<<NB_STAT, 256, 0, stream>>>(buf0, ps, ps2);
    k_stats2<<<1, 128, 0, stream>>>(ps, ps2, bn_g + 0, bn_b + 0, scb + 0, shb + 0);

    // ---- layer 1 ----
    k_mm128_fused<<<1024, 256, 0, stream>>>(buf0, scb + 0, shb + 0, w12, hh);
    k_agg_h<<<4096, 256, 0, stream>>>(hh, buf1, rp, col, wgt);
    k_stats1<<<NB_STAT, 256, 0, stream>>>(buf1, ps, ps2);
    k_stats2<<<1, 128, 0, stream>>>(ps, ps2, bn_g + 128, bn_b + 128, scb + 128, shb + 128);

    // ---- layer 2 ----
    k_mm128_fused<<<1024, 256, 0, stream>>>(buf1, scb + 128, shb + 128, w12 + 128 * 128, hh);
    k_agg_h<<<4096, 256, 0, stream>>>(hh, buf0, rp, col, wgt);
    k_stats1<<<NB_STAT, 256, 0, stream>>>(buf0, ps, ps2);
    k_stats2<<<1, 128, 0, stream>>>(ps, ps2, bn_g + 256, bn_b + 256, scb + 256, shb + 256);

    // ---- pool (fused BN+ReLU) + MLP ----
    k_pool_fused<<<NG / 4, 256, 0, stream>>>(buf0, scb + 256, shb + 256, batch, xg);
    k_mlp<<<NG / GPB, 256, 0, stream>>>(xg, m0w, m0b, m1w, m1b, m2w, m2b, out);
}

// Round 3
// 687.405 us; speedup vs baseline: 1.7615x; 1.2233x over previous
//
#include <hip/hip_runtime.h>
#include <hip/hip_fp16.h>

#define NN 100000
#define NE 1600000
#define NG 4096
#define HD 128
#define EPSV 1e-5f
#define NB_STAT 256
#define NBUCK 391            // ceil(NN/256)
#define BIN_CHUNK 4096
#define NBIN_BLK ((NE + BIN_CHUNK - 1) / BIN_CHUNK)   // 391
#define CSR_CAP 8448

// ---------------- bucketed CSR build ----------------

__global__ void k_zero_i32(int* p, int n) {
    int i = blockIdx.x * blockDim.x + threadIdx.x;
    if (i < n) p[i] = 0;
}

__global__ void k_bcount(const int* __restrict__ ei, int* __restrict__ bcnt) {
    __shared__ int cnt[NBUCK];
    int t = threadIdx.x;
    for (int i = t; i < NBUCK; i += 256) cnt[i] = 0;
    __syncthreads();
    int e0 = blockIdx.x * BIN_CHUNK;
    int e1 = min(NE, e0 + BIN_CHUNK);
    for (int e = e0 + t; e < e1; e += 256)
        atomicAdd(&cnt[ei[NE + e] >> 8], 1);
    __syncthreads();
    for (int i = t; i < NBUCK; i += 256)
        if (cnt[i]) atomicAdd(&bcnt[i], cnt[i]);
}

__global__ void k_bscan(const int* __restrict__ bcnt, int* __restrict__ ebase, int* __restrict__ gcur) {
    __shared__ int s[512];
    int t = threadIdx.x;
    int v = (t < NBUCK) ? bcnt[t] : 0;
    s[t] = v;
    __syncthreads();
    for (int off = 1; off < 512; off <<= 1) {
        int x = (t >= off) ? s[t - off] : 0;
        __syncthreads();
        s[t] += x;
        __syncthreads();
    }
    if (t <= NBUCK) {
        int ex = s[t] - v;
        ebase[t] = ex;
        if (t < NBUCK) gcur[t] = ex;
    }
}

__global__ void k_bin(const int* __restrict__ ei, int* __restrict__ gcur, unsigned* __restrict__ binned) {
    __shared__ int cnt[NBUCK];
    __shared__ int cur[NBUCK];
    int t = threadIdx.x;
    for (int i = t; i < NBUCK; i += 256) cnt[i] = 0;
    __syncthreads();
    int e0 = blockIdx.x * BIN_CHUNK;
    int e1 = min(NE, e0 + BIN_CHUNK);
    for (int e = e0 + t; e < e1; e += 256)
        atomicAdd(&cnt[ei[NE + e] >> 8], 1);
    __syncthreads();
    for (int i = t; i < NBUCK; i += 256)
        cur[i] = cnt[i] ? atomicAdd(&gcur[i], cnt[i]) : 0;
    __syncthreads();
    for (int e = e0 + t; e < e1; e += 256) {
        int d = ei[NE + e];
        int b = d >> 8;
        int r = atomicAdd(&cur[b], 1);
        binned[r] = ((unsigned)ei[e] << 8) | (unsigned)(d & 255);
    }
}

// one block per bucket: build rp, dinv, col (self-loop appended per row)
__global__ __launch_bounds__(256) void k_csr(const unsigned* __restrict__ binned,
        const int* __restrict__ ebase, int* __restrict__ rp,
        float* __restrict__ dinv, int* __restrict__ col) {
    __shared__ int colb[CSR_CAP];
    __shared__ int deg[256], off[256], cur[256], s[256];
    int b = blockIdx.x, t = threadIdx.x;
    int n0 = b * 256;
    int nodes = min(256, NN - n0);
    int cbeg = ebase[b];
    int cnt_b = min(ebase[b + 1] - cbeg, CSR_CAP - 256);
    int base = cbeg + n0;        // self-loops of earlier buckets = n0
    deg[t] = 0;
    __syncthreads();
    for (int i = t; i < cnt_b; i += 256)
        atomicAdd(&deg[binned[cbeg + i] & 255], 1);
    __syncthreads();
    int w = (t < nodes) ? deg[t] + 1 : 0;
    s[t] = w;
    __syncthreads();
    for (int o = 1; o < 256; o <<= 1) {
        int x = (t >= o) ? s[t - o] : 0;
        __syncthreads();
        s[t] += x;
        __syncthreads();
    }
    int ex = s[t] - w;
    off[t] = ex;
    cur[t] = ex;
    if (t < nodes) {
        rp[n0 + t] = base + ex;
        dinv[n0 + t] = rsqrtf((float)(deg[t] + 1));
    }
    __syncthreads();
    for (int i = t; i < cnt_b; i += 256) {
        unsigned pk = binned[cbeg + i];
        int d = pk & 255;
        int r = atomicAdd(&cur[d], 1);
        colb[r] = (int)(pk >> 8);
    }
    __syncthreads();
    if (t < nodes) colb[cur[t]] = n0 + t;    // self-loop at end of row
    __syncthreads();
    int tot = cnt_b + nodes;
    for (int i = t; i < tot; i += 256) col[base + i] = colb[i];
    if (b == 0 && t == 0) rp[NN] = NE + NN;
}

// ---------------- layer 0: (A·X)·W0 ----------------

// pad + pre-scale by dinv[n]: x16 [N,16]
__global__ void k_padx(const float* __restrict__ x, const float* __restrict__ dinv,
                       float* __restrict__ x16) {
    int i = blockIdx.x * blockDim.x + threadIdx.x;
    int n = i >> 4, c = i & 15;
    if (n >= NN) return;
    x16[i] = (c < 9) ? x[n * 9 + c] * dinv[n] : 0.f;
}

__global__ void k_aggx(const float* __restrict__ x16, const float* __restrict__ dinv,
                       float* __restrict__ aggx,
                       const int* __restrict__ rp, const int* __restrict__ col) {
    int t = blockIdx.x * blockDim.x + threadIdx.x;
    int n = t >> 2, sub = (t & 3) * 4;
    if (n >= NN) return;
    int s = rp[n], e = rp[n + 1];
    float dv = dinv[n];
    float4 acc = make_float4(0.f, 0.f, 0.f, 0.f);
    for (int i = s; i < e; ++i) {
        float4 v = *(const float4*)&x16[col[i] * 16 + sub];
        acc.x += v.x; acc.y += v.y; acc.z += v.z; acc.w += v.w;
    }
    acc.x *= dv; acc.y *= dv; acc.z *= dv; acc.w *= dv;
    *(float4*)&aggx[n * 16 + sub] = acc;
}

__global__ void k_mm9(const float* __restrict__ aggx, const float* __restrict__ w0,
                      float* __restrict__ gout) {
    int t = blockIdx.x * blockDim.x + threadIdx.x;
    int n = t >> 6, l = t & 63;
    if (n >= NN) return;
    int c = 2 * l;
    float2 acc = make_float2(0.f, 0.f);
#pragma unroll
    for (int k = 0; k < 9; ++k) {
        float a = aggx[n * 16 + k];
        float2 wv = *(const float2*)&w0[k * HD + c];
        acc.x += a * wv.x;
        acc.y += a * wv.y;
    }
    *(float2*)&gout[n * HD + c] = acc;
}

// ---------------- fused BN+ReLU matmul -> fp16 (row pre-scaled by dinv) ----------------

__global__ __launch_bounds__(256) void k_mm128_fused(const float* __restrict__ hin,
        const float* __restrict__ scale, const float* __restrict__ shift,
        const float* __restrict__ dinv,
        const float* __restrict__ W, __half* __restrict__ hout) {
    __shared__ __align__(16) float xs[4][8][HD];
    int t = threadIdx.x;
    int w = t >> 6, l = t & 63, c = 2 * l;
    float2 sc = make_float2(scale[c], scale[c + 1]);
    float2 sh = make_float2(shift[c], shift[c + 1]);
    int wid = blockIdx.x * 4 + w;
    int nw = gridDim.x * 4;
    for (int base = wid * 8; base < NN; base += nw * 8) {
#pragma unroll
        for (int j = 0; j < 8; ++j) {
            int n = base + j;
            float2 v = make_float2(0.f, 0.f);
            if (n < NN) {
                v = *(const float2*)&hin[n * HD + c];
                v.x = fmaxf(v.x * sc.x + sh.x, 0.f);
                v.y = fmaxf(v.y * sc.y + sh.y, 0.f);
            }
            *(float2*)&xs[w][j][c] = v;
        }
        float2 acc[8];
#pragma unroll
        for (int j = 0; j < 8; ++j) acc[j] = make_float2(0.f, 0.f);
        for (int k4 = 0; k4 < HD / 4; ++k4) {
            float4 a[8];
#pragma unroll
            for (int j = 0; j < 8; ++j) a[j] = *(const float4*)&xs[w][j][k4 * 4];
#pragma unroll
            for (int kk = 0; kk < 4; ++kk) {
                float2 wv = *(const float2*)&W[(k4 * 4 + kk) * HD + c];
#pragma unroll
                for (int j = 0; j < 8; ++j) {
                    float av = ((const float*)&a[j])[kk];
                    acc[j].x += av * wv.x;
                    acc[j].y += av * wv.y;
                }
            }
        }
#pragma unroll
        for (int j = 0; j < 8; ++j) {
            int n = base + j;
            if (n < NN) {
                float dv = dinv[n];
                *(__half2*)&hout[n * HD + c] = __floats2half2_rn(acc[j].x * dv, acc[j].y * dv);
            }
        }
    }
}

// CSR gather on fp16 rows; final scale by dinv[n]
__global__ void k_agg_h(const __half* __restrict__ hh, const float* __restrict__ dinv,
                        float* __restrict__ gout,
                        const int* __restrict__ rp, const int* __restrict__ col) {
    int l = threadIdx.x & 63;
    int wid = blockIdx.x * (blockDim.x >> 6) + (threadIdx.x >> 6);
    int nw = gridDim.x * (blockDim.x >> 6);
    int c = 2 * l;
    for (int n = wid; n < NN; n += nw) {
        int s = rp[n], e = rp[n + 1];
        float dv = dinv[n];
        float2 acc = make_float2(0.f, 0.f);
        int i = s;
        for (; i + 3 < e; i += 4) {
            int c0 = col[i], c1 = col[i + 1], c2 = col[i + 2], c3 = col[i + 3];
            float2 f0 = __half22float2(*(const __half2*)&hh[c0 * HD + c]);
            float2 f1 = __half22float2(*(const __half2*)&hh[c1 * HD + c]);
            float2 f2 = __half22float2(*(const __half2*)&hh[c2 * HD + c]);
            float2 f3 = __half22float2(*(const __half2*)&hh[c3 * HD + c]);
            acc.x += (f0.x + f1.x) + (f2.x + f3.x);
            acc.y += (f0.y + f1.y) + (f2.y + f3.y);
        }
        for (; i < e; ++i) {
            float2 f0 = __half22float2(*(const __half2*)&hh[col[i] * HD + c]);
            acc.x += f0.x;
            acc.y += f0.y;
        }
        *(float2*)&gout[n * HD + c] = make_float2(acc.x * dv, acc.y * dv);
    }
}

// ---------------- BN stats ----------------

__global__ void k_stats1(const float* __restrict__ h, double* __restrict__ ps, double* __restrict__ ps2) {
    __shared__ double sd[256], sd2[256];
    int b = blockIdx.x, t = threadIdx.x;
    int c = t & 127, half = t >> 7;
    const int chunk = (NN + NB_STAT - 1) / NB_STAT;  // 391
    int r0 = b * chunk;
    int r1 = min(NN, r0 + chunk);
    double s = 0.0, s2 = 0.0;
    for (int r = r0 + half; r < r1; r += 2) {
        float v = h[r * HD + c];
        s += v;
        s2 += (double)v * v;
    }
    sd[t] = s;
    sd2[t] = s2;
    __syncthreads();
    if (half == 0) {
        ps[b * 128 + c] = sd[t] + sd[t + 128];
        ps2[b * 128 + c] = sd2[t] + sd2[t + 128];
    }
}

__global__ void k_stats2(const double* __restrict__ ps, const double* __restrict__ ps2,
                         const float* __restrict__ g, const float* __restrict__ be,
                         float* __restrict__ scale, float* __restrict__ shift) {
    int c = threadIdx.x;
    double s = 0.0, s2 = 0.0;
    for (int b = 0; b < NB_STAT; ++b) {
        s += ps[b * 128 + c];
        s2 += ps2[b * 128 + c];
    }
    double mu = s / NN;
    double var = s2 / NN - mu * mu;
    float sc = g[c] * rsqrtf((float)var + EPSV);
    scale[c] = sc;
    shift[c] = be[c] - (float)mu * sc;
}

// ---------------- pooling (fused final BN+ReLU) + MLP ----------------

__global__ void k_pool_fused(const float* __restrict__ h, const float* __restrict__ scale,
                             const float* __restrict__ shift, const int* __restrict__ batch,
                             float* __restrict__ xg) {
    int l = threadIdx.x & 63;
    int g = blockIdx.x * (blockDim.x >> 6) + (threadIdx.x >> 6);
    if (g >= NG) return;
    int c = 2 * l;
    float2 sc = make_float2(scale[c], scale[c + 1]);
    float2 sh = make_float2(shift[c], shift[c + 1]);
    int lo = 0, hi = NN;
    while (lo < hi) { int m = (lo + hi) >> 1; if (batch[m] < g) lo = m + 1; else hi = m; }
    int s = lo;
    hi = NN;
    while (lo < hi) { int m = (lo + hi) >> 1; if (batch[m] < g + 1) lo = m + 1; else hi = m; }
    int e = lo;
    float2 sum = make_float2(0.f, 0.f), mx = make_float2(-3e38f, -3e38f);
    for (int r = s; r < e; ++r) {
        float2 v = *(const float2*)&h[r * HD + c];
        v.x = fmaxf(v.x * sc.x + sh.x, 0.f);
        v.y = fmaxf(v.y * sc.y + sh.y, 0.f);
        sum.x += v.x; sum.y += v.y;
        mx.x = fmaxf(mx.x, v.x); mx.y = fmaxf(mx.y, v.y);
    }
    float2 mean = make_float2(0.f, 0.f), mxo = make_float2(0.f, 0.f);
    if (e > s) {
        float cnt = (float)(e - s);
        mean.x = sum.x / cnt; mean.y = sum.y / cnt;
        mxo = mx;
    }
    *(float2*)&xg[g * 256 + c] = mean;
    *(float2*)&xg[g * 256 + 128 + c] = mxo;
}

#define GPB 8
__global__ __launch_bounds__(256) void k_mlp(const float* __restrict__ xg,
                                             const float* __restrict__ m0w, const float* __restrict__ m0b,
                                             const float* __restrict__ m1w, const float* __restrict__ m1b,
                                             const float* __restrict__ m2w, const float* __restrict__ m2b,
                                             float* __restrict__ out) {
    __shared__ float xs[GPB][256];
    __shared__ float h1[GPB][256];
    __shared__ float h2[GPB][64];
    int t = threadIdx.x;
    int g0 = blockIdx.x * GPB;
#pragma unroll
    for (int j = 0; j < GPB; ++j) xs[j][t] = xg[(g0 + j) * 256 + t];
    __syncthreads();
    float acc[GPB];
#pragma unroll
    for (int j = 0; j < GPB; ++j) acc[j] = m0b[t];
    for (int i = 0; i < 256; ++i) {
        float wv = m0w[i * 256 + t];
#pragma unroll
        for (int j = 0; j < GPB; ++j) acc[j] += xs[j][i] * wv;
    }
#pragma unroll
    for (int j = 0; j < GPB; ++j) h1[j][t] = fmaxf(acc[j], 0.f);
    __syncthreads();
    if (t < 64) {
        float a2[GPB];
#pragma unroll
        for (int j = 0; j < GPB; ++j) a2[j] = m1b[t];
        for (int i = 0; i < 256; ++i) {
            float wv = m1w[i * 64 + t];
#pragma unroll
            for (int j = 0; j < GPB; ++j) a2[j] += h1[j][i] * wv;
        }
#pragma unroll
        for (int j = 0; j < GPB; ++j) h2[j][t] = fmaxf(a2[j], 0.f);
    }
    __syncthreads();
    if (t < 64) {
#pragma unroll
        for (int j = 0; j < GPB; ++j) {
            float v = h2[j][t] * m2w[t];
            for (int off = 32; off; off >>= 1) v += __shfl_down(v, off);
            if (t == 0) out[g0 + j] = v + m2b[0];
        }
    }
}

// ---------------- launch ----------------

extern "C" void kernel_launch(void* const* d_in, const int* in_sizes, int n_in,
                              void* d_out, int out_size, void* d_ws, size_t ws_size,
                              hipStream_t stream) {
    const float* x    = (const float*)d_in[0];
    const int*   ei   = (const int*)d_in[1];
    const int*   batch= (const int*)d_in[2];
    const float* w0   = (const float*)d_in[3];
    const float* w12  = (const float*)d_in[4];
    // d_in[5] = cb : cancelled by BN mean-subtraction
    const float* bn_g = (const float*)d_in[6];
    const float* bn_b = (const float*)d_in[7];
    const float* m0w  = (const float*)d_in[8];
    const float* m0b  = (const float*)d_in[9];
    const float* m1w  = (const float*)d_in[10];
    const float* m1b  = (const float*)d_in[11];
    const float* m2w  = (const float*)d_in[12];
    const float* m2b  = (const float*)d_in[13];
    float* out = (float*)d_out;

    char* p = (char*)d_ws;
    auto alloc = [&](size_t bytes) {
        void* r = (void*)p;
        p += (bytes + 255) & ~(size_t)255;
        return r;
    };
    float*    buf0   = (float*)alloc((size_t)NN * HD * 4);
    float*    buf1   = (float*)alloc((size_t)NN * HD * 4);
    __half*   hh     = (__half*)alloc((size_t)NN * HD * 2);
    float*    x16    = (float*)alloc((size_t)NN * 16 * 4);
    float*    aggx   = (float*)alloc((size_t)NN * 16 * 4);
    float*    dinv   = (float*)alloc((size_t)NN * 4);
    int*      rp     = (int*)alloc((size_t)(NN + 1) * 4);
    int*      col    = (int*)alloc((size_t)(NE + NN) * 4);
    unsigned* binned = (unsigned*)alloc((size_t)NE * 4);
    int*      bcnt   = (int*)alloc(512 * 4);
    int*      ebase  = (int*)alloc(512 * 4);
    int*      gcur   = (int*)alloc(512 * 4);
    double*   ps     = (double*)alloc((size_t)NB_STAT * 128 * 8);
    double*   ps2    = (double*)alloc((size_t)NB_STAT * 128 * 8);
    float*    scb    = (float*)alloc(3 * 128 * 4);
    float*    shb    = (float*)alloc(3 * 128 * 4);
    float*    xg     = x16;  // x16 dead after k_aggx

    // ---- CSR build (bucketed, streaming) ----
    k_zero_i32<<<2, 256, 0, stream>>>(bcnt, 512);
    k_bcount<<<NBIN_BLK, 256, 0, stream>>>(ei, bcnt);
    k_bscan<<<1, 512, 0, stream>>>(bcnt, ebase, gcur);
    k_bin<<<NBIN_BLK, 256, 0, stream>>>(ei, gcur, binned);
    k_csr<<<NBUCK, 256, 0, stream>>>(binned, ebase, rp, dinv, col);

    // ---- layer 0 ----
    k_padx<<<(NN * 16 + 255) / 256, 256, 0, stream>>>(x, dinv, x16);
    k_aggx<<<(NN * 4 + 255) / 256, 256, 0, stream>>>(x16, dinv, aggx, rp, col);
    k_mm9<<<(NN * 64) / 256, 256, 0, stream>>>(aggx, w0, buf0);
    k_stats1<<<NB_STAT, 256, 0, stream>>>(buf0, ps, ps2);
    k_stats2<<<1, 128, 0, stream>>>(ps, ps2, bn_g + 0, bn_b + 0, scb + 0, shb + 0);

    // ---- layer 1 ----
    k_mm128_fused<<<1024, 256, 0, stream>>>(buf0, scb + 0, shb + 0, dinv, w12, hh);
    k_agg_h<<<4096, 256, 0, stream>>>(hh, dinv, buf1, rp, col);
    k_stats1<<<NB_STAT, 256, 0, stream>>>(buf1, ps, ps2);
    k_stats2<<<1, 128, 0, stream>>>(ps, ps2, bn_g + 128, bn_b + 128, scb + 128, shb + 128);

    // ---- layer 2 ----
    k_mm128_fused<<<1024, 256, 0, stream>>>(buf1, scb + 128, shb + 128, dinv, w12 + 128 * 128, hh);
    k_agg_h<<<4096, 256, 0, stream>>>(hh, dinv, buf0, rp, col);
    k_stats1<<<NB_STAT, 256, 0, stream>>>(buf0, ps, ps2);
    k_stats2<<<1, 128, 0, stream>>>(ps, ps2, bn_g + 256, bn_b + 256, scb + 256, shb + 256);

    // ---- pool (fused BN+ReLU) + MLP ----
    k_pool_fused<<<NG / 4, 256, 0, stream>>>(buf0, scb + 256, shb + 256, batch, xg);
    k_mlp<<<NG / GPB, 256, 0, stream>>>(xg, m0w, m0b, m1w, m1b, m2w, m2b, out);
}

// Round 4
// 574.673 us; speedup vs baseline: 2.1070x; 1.1962x over previous
//
#include <hip/hip_runtime.h>

#define NN 100000
#define NE 1600000
#define NG 4096
#define HD 128
#define EPSV 1e-5f
#define NBUCK 391            // ceil(NN/256)
#define BIN_CHUNK 4096
#define NBIN_BLK ((NE + BIN_CHUNK - 1) / BIN_CHUNK)   // 391
#define CSR_CAP 8448
#define NBA 1024             // stats partial blocks
#define CHUNK 98             // ceil(NN/NBA)

typedef _Float16 half_t;
typedef _Float16 half8 __attribute__((ext_vector_type(8)));
typedef _Float16 half2v __attribute__((ext_vector_type(2)));
typedef float f32x4 __attribute__((ext_vector_type(4)));

// ---------------- bucketed CSR build ----------------

__global__ void k_zero_i32(int* p, int n) {
    int i = blockIdx.x * blockDim.x + threadIdx.x;
    if (i < n) p[i] = 0;
}

__global__ void k_bcount(const int* __restrict__ ei, int* __restrict__ bcnt) {
    __shared__ int cnt[NBUCK];
    int t = threadIdx.x;
    for (int i = t; i < NBUCK; i += 256) cnt[i] = 0;
    __syncthreads();
    int e0 = blockIdx.x * BIN_CHUNK;
    int e1 = min(NE, e0 + BIN_CHUNK);
    for (int e = e0 + t; e < e1; e += 256)
        atomicAdd(&cnt[ei[NE + e] >> 8], 1);
    __syncthreads();
    for (int i = t; i < NBUCK; i += 256)
        if (cnt[i]) atomicAdd(&bcnt[i], cnt[i]);
}

__global__ void k_bscan(const int* __restrict__ bcnt, int* __restrict__ ebase, int* __restrict__ gcur) {
    __shared__ int s[512];
    int t = threadIdx.x;
    int v = (t < NBUCK) ? bcnt[t] : 0;
    s[t] = v;
    __syncthreads();
    for (int off = 1; off < 512; off <<= 1) {
        int x = (t >= off) ? s[t - off] : 0;
        __syncthreads();
        s[t] += x;
        __syncthreads();
    }
    if (t <= NBUCK) {
        int ex = s[t] - v;
        ebase[t] = ex;
        if (t < NBUCK) gcur[t] = ex;
    }
}

__global__ void k_bin(const int* __restrict__ ei, int* __restrict__ gcur, unsigned* __restrict__ binned) {
    __shared__ int cnt[NBUCK];
    __shared__ int cur[NBUCK];
    int t = threadIdx.x;
    for (int i = t; i < NBUCK; i += 256) cnt[i] = 0;
    __syncthreads();
    int e0 = blockIdx.x * BIN_CHUNK;
    int e1 = min(NE, e0 + BIN_CHUNK);
    for (int e = e0 + t; e < e1; e += 256)
        atomicAdd(&cnt[ei[NE + e] >> 8], 1);
    __syncthreads();
    for (int i = t; i < NBUCK; i += 256)
        cur[i] = cnt[i] ? atomicAdd(&gcur[i], cnt[i]) : 0;
    __syncthreads();
    for (int e = e0 + t; e < e1; e += 256) {
        int d = ei[NE + e];
        int b = d >> 8;
        int r = atomicAdd(&cur[b], 1);
        binned[r] = ((unsigned)ei[e] << 8) | (unsigned)(d & 255);
    }
}

__global__ __launch_bounds__(256) void k_csr(const unsigned* __restrict__ binned,
        const int* __restrict__ ebase, int* __restrict__ rp,
        float* __restrict__ dinv, int* __restrict__ col) {
    __shared__ int colb[CSR_CAP];
    __shared__ int deg[256], off[256], cur[256], s[256];
    int b = blockIdx.x, t = threadIdx.x;
    int n0 = b * 256;
    int nodes = min(256, NN - n0);
    int cbeg = ebase[b];
    int cnt_b = min(ebase[b + 1] - cbeg, CSR_CAP - 256);
    int base = cbeg + n0;
    deg[t] = 0;
    __syncthreads();
    for (int i = t; i < cnt_b; i += 256)
        atomicAdd(&deg[binned[cbeg + i] & 255], 1);
    __syncthreads();
    int w = (t < nodes) ? deg[t] + 1 : 0;
    s[t] = w;
    __syncthreads();
    for (int o = 1; o < 256; o <<= 1) {
        int x = (t >= o) ? s[t - o] : 0;
        __syncthreads();
        s[t] += x;
        __syncthreads();
    }
    int ex = s[t] - w;
    off[t] = ex;
    cur[t] = ex;
    if (t < nodes) {
        rp[n0 + t] = base + ex;
        dinv[n0 + t] = rsqrtf((float)(deg[t] + 1));
    }
    __syncthreads();
    for (int i = t; i < cnt_b; i += 256) {
        unsigned pk = binned[cbeg + i];
        int d = pk & 255;
        int r = atomicAdd(&cur[d], 1);
        colb[r] = (int)(pk >> 8);
    }
    __syncthreads();
    if (t < nodes) colb[cur[t]] = n0 + t;
    __syncthreads();
    int tot = cnt_b + nodes;
    for (int i = t; i < tot; i += 256) col[base + i] = colb[i];
    if (b == 0 && t == 0) rp[NN] = NE + NN;
}

// ---------------- weight prep: Wt[m][n][k] = w12[m][k][n] as fp16 ----------------

__global__ void k_cvtw(const float* __restrict__ w12, half_t* __restrict__ Wt) {
    int i = blockIdx.x * 256 + threadIdx.x;   // 32768
    int m = i >> 14;
    int r = i & 16383;
    int n = r >> 7, k = r & 127;
    Wt[i] = (half_t)w12[m * 16384 + k * 128 + n];
}

// ---------------- layer 0 ----------------

// x [N,9] -> xh fp16 [N,16], pre-scaled by dinv
__global__ void k_padx(const float* __restrict__ x, const float* __restrict__ dinv,
                       half_t* __restrict__ xh) {
    int n = blockIdx.x * 256 + threadIdx.x;
    if (n >= NN) return;
    float dv = dinv[n];
    half_t buf[16];
#pragma unroll
    for (int k = 0; k < 9; ++k) buf[k] = (half_t)(x[n * 9 + k] * dv);
#pragma unroll
    for (int k = 9; k < 16; ++k) buf[k] = (half_t)0.f;
    *(half8*)&xh[n * 16] = *(half8*)buf;
    *(half8*)&xh[n * 16 + 8] = *(half8*)(buf + 8);
}

// gather fp16 16-elem rows; 2 lanes per node
__global__ void k_aggx(const half_t* __restrict__ xh, const float* __restrict__ dinv,
                       float* __restrict__ aggx,
                       const int* __restrict__ rp, const int* __restrict__ col) {
    int t = blockIdx.x * blockDim.x + threadIdx.x;
    int n = t >> 1, sub = (t & 1) * 8;
    if (n >= NN) return;
    int s = rp[n], e = rp[n + 1];
    float acc[8];
#pragma unroll
    for (int j = 0; j < 8; ++j) acc[j] = 0.f;
    for (int i = s; i < e; ++i) {
        half8 v = *(const half8*)&xh[col[i] * 16 + sub];
#pragma unroll
        for (int j = 0; j < 8; ++j) acc[j] += (float)v[j];
    }
    float dv = dinv[n];
    f32x4 o0 = {acc[0] * dv, acc[1] * dv, acc[2] * dv, acc[3] * dv};
    f32x4 o1 = {acc[4] * dv, acc[5] * dv, acc[6] * dv, acc[7] * dv};
    *(f32x4*)&aggx[n * 16 + sub] = o0;
    *(f32x4*)&aggx[n * 16 + sub + 4] = o1;
}

// aggx [N,16(9)] @ w0 [9,128] -> gf fp16 + fused stats partials
__global__ __launch_bounds__(256) void k_mm9(const float* __restrict__ aggx,
        const float* __restrict__ w0, half_t* __restrict__ gout,
        float* __restrict__ ps, float* __restrict__ ps2) {
    __shared__ float lsum[4][128], lsq[4][128];
    int t = threadIdx.x, w = t >> 6, l = t & 63;
    int c = 2 * l;
    int n0 = blockIdx.x * CHUNK;
    int n1 = min(NN, n0 + CHUNK);
    float s0 = 0.f, s1 = 0.f, q0 = 0.f, q1 = 0.f;
    for (int n = n0 + w; n < n1; n += 4) {
        float2 acc = make_float2(0.f, 0.f);
#pragma unroll
        for (int k = 0; k < 9; ++k) {
            float a = aggx[n * 16 + k];
            float2 wv = *(const float2*)&w0[k * HD + c];
            acc.x += a * wv.x;
            acc.y += a * wv.y;
        }
        half_t hx = (half_t)acc.x, hy = (half_t)acc.y;
        half2v hv = {hx, hy};
        *(half2v*)&gout[n * HD + c] = hv;
        float fx = (float)hx, fy = (float)hy;
        s0 += fx; q0 += fx * fx; s1 += fy; q1 += fy * fy;
    }
    lsum[w][c] = s0; lsum[w][c + 1] = s1;
    lsq[w][c] = q0;  lsq[w][c + 1] = q1;
    __syncthreads();
    if (t < 128) {
        ps[blockIdx.x * 128 + t] = lsum[0][t] + lsum[1][t] + lsum[2][t] + lsum[3][t];
        ps2[blockIdx.x * 128 + t] = lsq[0][t] + lsq[1][t] + lsq[2][t] + lsq[3][t];
    }
}

__global__ void k_stats2(const float* __restrict__ ps, const float* __restrict__ ps2,
                         const float* __restrict__ g, const float* __restrict__ be,
                         float* __restrict__ scale, float* __restrict__ shift) {
    int c = threadIdx.x;   // 128
    double s = 0.0, s2 = 0.0;
    for (int b = 0; b < NBA; ++b) {
        s += (double)ps[b * 128 + c];
        s2 += (double)ps2[b * 128 + c];
    }
    double mu = s / NN;
    double var = s2 / NN - mu * mu;
    float sc = g[c] * rsqrtf((float)var + EPSV);
    scale[c] = sc;
    shift[c] = be[c] - (float)mu * sc;
}

// ---------------- MFMA matmul: hh = relu(bn(gf)) @ W · dinv, fp16 out ----------------

__global__ __launch_bounds__(256) void k_mm_mfma(const half_t* __restrict__ gf,
        const float* __restrict__ scale, const float* __restrict__ shift,
        const float* __restrict__ dinv, const half_t* __restrict__ Wt,
        half_t* __restrict__ hh) {
    __shared__ half_t wlds[16384];   // [n][k] fp16, 16B-XOR swizzled
    int t = threadIdx.x;
#pragma unroll
    for (int j = 0; j < 8; ++j) {
        int cidx = t * 8 + j;          // 16-B chunk
        int n = cidx >> 4, k8 = cidx & 15;
        half8 v = *(const half8*)&Wt[cidx * 8];
        int byte = n * 256 + ((k8 * 16) ^ ((n & 7) << 4));
        *(half8*)((char*)wlds + byte) = v;
    }
    __syncthreads();
    int w = t >> 6, l = t & 63;
    int lr = l & 15, lg = l >> 4;
    int base = (blockIdx.x * 4 + w) * 16;
    int row = base + lr;
    bool rowok = row < NN;
    f32x4 acc[8];
#pragma unroll
    for (int nt = 0; nt < 8; ++nt) acc[nt] = (f32x4){0.f, 0.f, 0.f, 0.f};
#pragma unroll
    for (int kk = 0; kk < 4; ++kk) {
        int ch0 = kk * 32 + lg * 8;
        half8 a8;
        if (rowok) {
            half8 hv = *(const half8*)&gf[row * HD + ch0];
            f32x4 sc0 = *(const f32x4*)&scale[ch0];
            f32x4 sc1 = *(const f32x4*)&scale[ch0 + 4];
            f32x4 sh0 = *(const f32x4*)&shift[ch0];
            f32x4 sh1 = *(const f32x4*)&shift[ch0 + 4];
#pragma unroll
            for (int i = 0; i < 4; ++i)
                a8[i] = (half_t)fmaxf((float)hv[i] * sc0[i] + sh0[i], 0.f);
#pragma unroll
            for (int i = 0; i < 4; ++i)
                a8[4 + i] = (half_t)fmaxf((float)hv[4 + i] * sc1[i] + sh1[i], 0.f);
        } else {
#pragma unroll
            for (int i = 0; i < 8; ++i) a8[i] = (half_t)0.f;
        }
        int kbyte = kk * 64 + lg * 16;
#pragma unroll
        for (int nt = 0; nt < 8; ++nt) {
            int n = nt * 16 + lr;
            half8 b8 = *(const half8*)((const char*)wlds + n * 256 + (kbyte ^ ((n & 7) << 4)));
            acc[nt] = __builtin_amdgcn_mfma_f32_16x16x32_f16(a8, b8, acc[nt], 0, 0, 0);
        }
    }
    // D: col = 16*nt + lr, row = base + lg*4 + i
#pragma unroll
    for (int i = 0; i < 4; ++i) {
        int r = base + lg * 4 + i;
        if (r < NN) {
            float dv = dinv[r];
#pragma unroll
            for (int nt = 0; nt < 8; ++nt)
                hh[r * HD + nt * 16 + lr] = (half_t)(acc[nt][i] * dv);
        }
    }
}

// ---------------- fp16 CSR gather + fused stats ----------------

__global__ __launch_bounds__(256) void k_agg_h(const half_t* __restrict__ hh,
        const float* __restrict__ dinv, half_t* __restrict__ gout,
        const int* __restrict__ rp, const int* __restrict__ col,
        float* __restrict__ ps, float* __restrict__ ps2) {
    __shared__ float lsum[4][128], lsq[4][128];
    int t = threadIdx.x, w = t >> 6, l = t & 63;
    int c = 2 * l;
    int n0 = blockIdx.x * CHUNK;
    int n1 = min(NN, n0 + CHUNK);
    float s0 = 0.f, s1 = 0.f, q0 = 0.f, q1 = 0.f;
    for (int n = n0 + w; n < n1; n += 4) {
        int s = rp[n], e = rp[n + 1];
        float dv = dinv[n];
        float ax = 0.f, ay = 0.f;
        int i = s;
        for (; i + 3 < e; i += 4) {
            int c0 = col[i], c1 = col[i + 1], c2 = col[i + 2], c3 = col[i + 3];
            half2v v0 = *(const half2v*)&hh[c0 * HD + c];
            half2v v1 = *(const half2v*)&hh[c1 * HD + c];
            half2v v2 = *(const half2v*)&hh[c2 * HD + c];
            half2v v3 = *(const half2v*)&hh[c3 * HD + c];
            ax += ((float)v0[0] + (float)v1[0]) + ((float)v2[0] + (float)v3[0]);
            ay += ((float)v0[1] + (float)v1[1]) + ((float)v2[1] + (float)v3[1]);
        }
        for (; i < e; ++i) {
            half2v v0 = *(const half2v*)&hh[col[i] * HD + c];
            ax += (float)v0[0];
            ay += (float)v0[1];
        }
        half_t hx = (half_t)(ax * dv), hy = (half_t)(ay * dv);
        half2v hv = {hx, hy};
        *(half2v*)&gout[n * HD + c] = hv;
        float fx = (float)hx, fy = (float)hy;
        s0 += fx; q0 += fx * fx; s1 += fy; q1 += fy * fy;
    }
    lsum[w][c] = s0; lsum[w][c + 1] = s1;
    lsq[w][c] = q0;  lsq[w][c + 1] = q1;
    __syncthreads();
    if (t < 128) {
        ps[blockIdx.x * 128 + t] = lsum[0][t] + lsum[1][t] + lsum[2][t] + lsum[3][t];
        ps2[blockIdx.x * 128 + t] = lsq[0][t] + lsq[1][t] + lsq[2][t] + lsq[3][t];
    }
}

// ---------------- pooling (fused final BN+ReLU) + MLP ----------------

__global__ void k_pool_fused(const half_t* __restrict__ h, const float* __restrict__ scale,
                             const float* __restrict__ shift, const int* __restrict__ batch,
                             float* __restrict__ xg) {
    int l = threadIdx.x & 63;
    int g = blockIdx.x * (blockDim.x >> 6) + (threadIdx.x >> 6);
    if (g >= NG) return;
    int c = 2 * l;
    float2 sc = make_float2(scale[c], scale[c + 1]);
    float2 sh = make_float2(shift[c], shift[c + 1]);
    int lo = 0, hi = NN;
    while (lo < hi) { int m = (lo + hi) >> 1; if (batch[m] < g) lo = m + 1; else hi = m; }
    int s = lo;
    hi = NN;
    while (lo < hi) { int m = (lo + hi) >> 1; if (batch[m] < g + 1) lo = m + 1; else hi = m; }
    int e = lo;
    float2 sum = make_float2(0.f, 0.f), mx = make_float2(-3e38f, -3e38f);
    for (int r = s; r < e; ++r) {
        half2v hv = *(const half2v*)&h[r * HD + c];
        float vx = fmaxf((float)hv[0] * sc.x + sh.x, 0.f);
        float vy = fmaxf((float)hv[1] * sc.y + sh.y, 0.f);
        sum.x += vx; sum.y += vy;
        mx.x = fmaxf(mx.x, vx); mx.y = fmaxf(mx.y, vy);
    }
    float2 mean = make_float2(0.f, 0.f), mxo = make_float2(0.f, 0.f);
    if (e > s) {
        float cnt = (float)(e - s);
        mean.x = sum.x / cnt; mean.y = sum.y / cnt;
        mxo = mx;
    }
    *(float2*)&xg[g * 256 + c] = mean;
    *(float2*)&xg[g * 256 + 128 + c] = mxo;
}

#define GPB 8
__global__ __launch_bounds__(256) void k_mlp(const float* __restrict__ xg,
                                             const float* __restrict__ m0w, const float* __restrict__ m0b,
                                             const float* __restrict__ m1w, const float* __restrict__ m1b,
                                             const float* __restrict__ m2w, const float* __restrict__ m2b,
                                             float* __restrict__ out) {
    __shared__ float xs[GPB][256];
    __shared__ float h1[GPB][256];
    __shared__ float h2[GPB][64];
    int t = threadIdx.x;
    int g0 = blockIdx.x * GPB;
#pragma unroll
    for (int j = 0; j < GPB; ++j) xs[j][t] = xg[(g0 + j) * 256 + t];
    __syncthreads();
    float acc[GPB];
#pragma unroll
    for (int j = 0; j < GPB; ++j) acc[j] = m0b[t];
    for (int i = 0; i < 256; ++i) {
        float wv = m0w[i * 256 + t];
#pragma unroll
        for (int j = 0; j < GPB; ++j) acc[j] += xs[j][i] * wv;
    }
#pragma unroll
    for (int j = 0; j < GPB; ++j) h1[j][t] = fmaxf(acc[j], 0.f);
    __syncthreads();
    if (t < 64) {
        float a2[GPB];
#pragma unroll
        for (int j = 0; j < GPB; ++j) a2[j] = m1b[t];
        for (int i = 0; i < 256; ++i) {
            float wv = m1w[i * 64 + t];
#pragma unroll
            for (int j = 0; j < GPB; ++j) a2[j] += h1[j][i] * wv;
        }
#pragma unroll
        for (int j = 0; j < GPB; ++j) h2[j][t] = fmaxf(a2[j], 0.f);
    }
    __syncthreads();
    if (t < 64) {
#pragma unroll
        for (int j = 0; j < GPB; ++j) {
            float v = h2[j][t] * m2w[t];
            for (int off = 32; off; off >>= 1) v += __shfl_down(v, off);
            if (t == 0) out[g0 + j] = v + m2b[0];
        }
    }
}

// ---------------- launch ----------------

extern "C" void kernel_launch(void* const* d_in, const int* in_sizes, int n_in,
                              void* d_out, int out_size, void* d_ws, size_t ws_size,
                              hipStream_t stream) {
    const float* x    = (const float*)d_in[0];
    const int*   ei   = (const int*)d_in[1];
    const int*   batch= (const int*)d_in[2];
    const float* w0   = (const float*)d_in[3];
    const float* w12  = (const float*)d_in[4];
    // d_in[5] = cb : cancelled by BN mean-subtraction
    const float* bn_g = (const float*)d_in[6];
    const float* bn_b = (const float*)d_in[7];
    const float* m0w  = (const float*)d_in[8];
    const float* m0b  = (const float*)d_in[9];
    const float* m1w  = (const float*)d_in[10];
    const float* m1b  = (const float*)d_in[11];
    const float* m2w  = (const float*)d_in[12];
    const float* m2b  = (const float*)d_in[13];
    float* out = (float*)d_out;

    char* p = (char*)d_ws;
    auto alloc = [&](size_t bytes) {
        void* r = (void*)p;
        p += (bytes + 255) & ~(size_t)255;
        return r;
    };
    half_t*   gf0    = (half_t*)alloc((size_t)NN * HD * 2);
    half_t*   gf1    = (half_t*)alloc((size_t)NN * HD * 2);
    half_t*   hh     = (half_t*)alloc((size_t)NN * HD * 2);
    half_t*   xh     = (half_t*)alloc((size_t)NN * 16 * 2);
    float*    aggx   = (float*)alloc((size_t)NN * 16 * 4);
    half_t*   Wt     = (half_t*)alloc((size_t)2 * 128 * 128 * 2);
    float*    dinv   = (float*)alloc((size_t)NN * 4);
    int*      rp     = (int*)alloc((size_t)(NN + 1) * 4);
    int*      col    = (int*)alloc((size_t)(NE + NN) * 4);
    unsigned* binned = (unsigned*)alloc((size_t)NE * 4);
    int*      bcnt   = (int*)alloc(512 * 4);
    int*      ebase  = (int*)alloc(512 * 4);
    int*      gcur   = (int*)alloc(512 * 4);
    float*    ps     = (float*)alloc((size_t)NBA * 128 * 4);
    float*    ps2    = (float*)alloc((size_t)NBA * 128 * 4);
    float*    scb    = (float*)alloc(3 * 128 * 4);
    float*    shb    = (float*)alloc(3 * 128 * 4);
    float*    xg     = (float*)alloc((size_t)NG * 256 * 4);

    // ---- CSR build ----
    k_zero_i32<<<2, 256, 0, stream>>>(bcnt, 512);
    k_bcount<<<NBIN_BLK, 256, 0, stream>>>(ei, bcnt);
    k_bscan<<<1, 512, 0, stream>>>(bcnt, ebase, gcur);
    k_bin<<<NBIN_BLK, 256, 0, stream>>>(ei, gcur, binned);
    k_csr<<<NBUCK, 256, 0, stream>>>(binned, ebase, rp, dinv, col);

    // ---- weight prep ----
    k_cvtw<<<128, 256, 0, stream>>>(w12, Wt);

    // ---- layer 0 ----
    k_padx<<<(NN + 255) / 256, 256, 0, stream>>>(x, dinv, xh);
    k_aggx<<<(NN * 2 + 255) / 256, 256, 0, stream>>>(xh, dinv, aggx, rp, col);
    k_mm9<<<NBA, 256, 0, stream>>>(aggx, w0, gf0, ps, ps2);
    k_stats2<<<1, 128, 0, stream>>>(ps, ps2, bn_g + 0, bn_b + 0, scb + 0, shb + 0);

    // ---- layer 1 ----
    k_mm_mfma<<<(NN + 63) / 64, 256, 0, stream>>>(gf0, scb + 0, shb + 0, dinv, Wt, hh);
    k_agg_h<<<NBA, 256, 0, stream>>>(hh, dinv, gf1, rp, col, ps, ps2);
    k_stats2<<<1, 128, 0, stream>>>(ps, ps2, bn_g + 128, bn_b + 128, scb + 128, shb + 128);

    // ---- layer 2 ----
    k_mm_mfma<<<(NN + 63) / 64, 256, 0, stream>>>(gf1, scb + 128, shb + 128, dinv, Wt + 16384, hh);
    k_agg_h<<<NBA, 256, 0, stream>>>(hh, dinv, gf0, rp, col, ps, ps2);
    k_stats2<<<1, 128, 0, stream>>>(ps, ps2, bn_g + 256, bn_b + 256, scb + 256, shb + 256);

    // ---- pool + MLP ----
    k_pool_fused<<<NG / 4, 256, 0, stream>>>(gf0, scb + 256, shb + 256, batch, xg);
    k_mlp<<<NG / GPB, 256, 0, stream>>>(xg, m0w, m0b, m1w, m1b, m2w, m2b, out);
}

// Round 5
// 368.381 us; speedup vs baseline: 3.2869x; 1.5600x over previous
//
#include <hip/hip_runtime.h>

#define NN 100000
#define NE 1600000
#define NG 4096
#define HD 128
#define EPSV 1e-5f
#define NBUCK 391            // ceil(NN/256)
#define BIN_CHUNK 4096
#define NBIN_BLK ((NE + BIN_CHUNK - 1) / BIN_CHUNK)   // 391
#define CSR_CAP 8448
#define NB_AG 4096           // agg stats blocks
#define CH_AG 25             // ceil(NN/NB_AG)
#define NB_MM 2048           // mm9 stats blocks
#define CH_MM 49             // ceil(NN/NB_MM)

typedef _Float16 half_t;
typedef _Float16 half8 __attribute__((ext_vector_type(8)));
typedef _Float16 half4v __attribute__((ext_vector_type(4)));
typedef _Float16 half2v __attribute__((ext_vector_type(2)));
typedef float f32x4 __attribute__((ext_vector_type(4)));

// ---------------- bucketed CSR build ----------------

__global__ void k_zero_i32(int* p, int n) {
    int i = blockIdx.x * blockDim.x + threadIdx.x;
    if (i < n) p[i] = 0;
}

__global__ void k_bcount(const int* __restrict__ ei, int* __restrict__ bcnt) {
    __shared__ int cnt[NBUCK];
    int t = threadIdx.x;
    for (int i = t; i < NBUCK; i += 256) cnt[i] = 0;
    __syncthreads();
    int e0 = blockIdx.x * BIN_CHUNK;
    int e1 = min(NE, e0 + BIN_CHUNK);
    for (int e = e0 + t; e < e1; e += 256)
        atomicAdd(&cnt[ei[NE + e] >> 8], 1);
    __syncthreads();
    for (int i = t; i < NBUCK; i += 256)
        if (cnt[i]) atomicAdd(&bcnt[i], cnt[i]);
}

__global__ void k_bscan(const int* __restrict__ bcnt, int* __restrict__ ebase, int* __restrict__ gcur) {
    __shared__ int s[512];
    int t = threadIdx.x;
    int v = (t < NBUCK) ? bcnt[t] : 0;
    s[t] = v;
    __syncthreads();
    for (int off = 1; off < 512; off <<= 1) {
        int x = (t >= off) ? s[t - off] : 0;
        __syncthreads();
        s[t] += x;
        __syncthreads();
    }
    if (t <= NBUCK) {
        int ex = s[t] - v;
        ebase[t] = ex;
        if (t < NBUCK) gcur[t] = ex;
    }
}

__global__ void k_bin(const int* __restrict__ ei, int* __restrict__ gcur, unsigned* __restrict__ binned) {
    __shared__ int cnt[NBUCK];
    __shared__ int cur[NBUCK];
    int t = threadIdx.x;
    for (int i = t; i < NBUCK; i += 256) cnt[i] = 0;
    __syncthreads();
    int e0 = blockIdx.x * BIN_CHUNK;
    int e1 = min(NE, e0 + BIN_CHUNK);
    for (int e = e0 + t; e < e1; e += 256)
        atomicAdd(&cnt[ei[NE + e] >> 8], 1);
    __syncthreads();
    for (int i = t; i < NBUCK; i += 256)
        cur[i] = cnt[i] ? atomicAdd(&gcur[i], cnt[i]) : 0;
    __syncthreads();
    for (int e = e0 + t; e < e1; e += 256) {
        int d = ei[NE + e];
        int b = d >> 8;
        int r = atomicAdd(&cur[b], 1);
        binned[r] = ((unsigned)ei[e] << 8) | (unsigned)(d & 255);
    }
}

__global__ __launch_bounds__(256) void k_csr(const unsigned* __restrict__ binned,
        const int* __restrict__ ebase, int* __restrict__ rp,
        float* __restrict__ dinv, int* __restrict__ col) {
    __shared__ int colb[CSR_CAP];
    __shared__ int deg[256], off[256], cur[256], s[256];
    int b = blockIdx.x, t = threadIdx.x;
    int n0 = b * 256;
    int nodes = min(256, NN - n0);
    int cbeg = ebase[b];
    int cnt_b = min(ebase[b + 1] - cbeg, CSR_CAP - 256);
    int base = cbeg + n0;
    deg[t] = 0;
    __syncthreads();
    for (int i = t; i < cnt_b; i += 256)
        atomicAdd(&deg[binned[cbeg + i] & 255], 1);
    __syncthreads();
    int w = (t < nodes) ? deg[t] + 1 : 0;
    s[t] = w;
    __syncthreads();
    for (int o = 1; o < 256; o <<= 1) {
        int x = (t >= o) ? s[t - o] : 0;
        __syncthreads();
        s[t] += x;
        __syncthreads();
    }
    int ex = s[t] - w;
    off[t] = ex;
    cur[t] = ex;
    if (t < nodes) {
        rp[n0 + t] = base + ex;
        dinv[n0 + t] = rsqrtf((float)(deg[t] + 1));
    }
    __syncthreads();
    for (int i = t; i < cnt_b; i += 256) {
        unsigned pk = binned[cbeg + i];
        int d = pk & 255;
        int r = atomicAdd(&cur[d], 1);
        colb[r] = (int)(pk >> 8);
    }
    __syncthreads();
    if (t < nodes) colb[cur[t]] = n0 + t;
    __syncthreads();
    int tot = cnt_b + nodes;
    for (int i = t; i < tot; i += 256) col[base + i] = colb[i];
    if (b == 0 && t == 0) rp[NN] = NE + NN;
}

// ---------------- weight prep: Wt[m][n][k] = w12[m][k][n] as fp16 ----------------

__global__ void k_cvtw(const float* __restrict__ w12, half_t* __restrict__ Wt) {
    int i = blockIdx.x * 256 + threadIdx.x;   // 32768
    int m = i >> 14;
    int r = i & 16383;
    int n = r >> 7, k = r & 127;
    Wt[i] = (half_t)w12[m * 16384 + k * 128 + n];
}

// ---------------- layer 0 ----------------

__global__ void k_padx(const float* __restrict__ x, const float* __restrict__ dinv,
                       half_t* __restrict__ xh) {
    int n = blockIdx.x * 256 + threadIdx.x;
    if (n >= NN) return;
    float dv = dinv[n];
    half_t buf[16];
#pragma unroll
    for (int k = 0; k < 9; ++k) buf[k] = (half_t)(x[n * 9 + k] * dv);
#pragma unroll
    for (int k = 9; k < 16; ++k) buf[k] = (half_t)0.f;
    *(half8*)&xh[n * 16] = *(half8*)buf;
    *(half8*)&xh[n * 16 + 8] = *(half8*)(buf + 8);
}

// 4 lanes per node, half4 (8B) per lane
__global__ void k_aggx(const half_t* __restrict__ xh, const float* __restrict__ dinv,
                       float* __restrict__ aggx,
                       const int* __restrict__ rp, const int* __restrict__ col) {
    int t = blockIdx.x * blockDim.x + threadIdx.x;
    int n = t >> 2, sub = (t & 3) * 4;
    if (n >= NN) return;
    int s = rp[n], e = rp[n + 1];
    float acc[4] = {0.f, 0.f, 0.f, 0.f};
    int i = s;
    for (; i + 1 < e; i += 2) {
        half4v v0 = *(const half4v*)&xh[col[i] * 16 + sub];
        half4v v1 = *(const half4v*)&xh[col[i + 1] * 16 + sub];
#pragma unroll
        for (int j = 0; j < 4; ++j) acc[j] += (float)v0[j] + (float)v1[j];
    }
    if (i < e) {
        half4v v0 = *(const half4v*)&xh[col[i] * 16 + sub];
#pragma unroll
        for (int j = 0; j < 4; ++j) acc[j] += (float)v0[j];
    }
    float dv = dinv[n];
    f32x4 o = {acc[0] * dv, acc[1] * dv, acc[2] * dv, acc[3] * dv};
    *(f32x4*)&aggx[n * 16 + sub] = o;
}

// aggx [N,16(9)] @ w0 [9,128] -> gf fp16 + fused stats partials
__global__ __launch_bounds__(256) void k_mm9(const float* __restrict__ aggx,
        const float* __restrict__ w0, half_t* __restrict__ gout,
        float* __restrict__ ps, float* __restrict__ ps2) {
    __shared__ float lsum[4][128], lsq[4][128];
    int t = threadIdx.x, w = t >> 6, l = t & 63;
    int c = 2 * l;
    int n0 = blockIdx.x * CH_MM;
    int n1 = min(NN, n0 + CH_MM);
    float s0 = 0.f, s1 = 0.f, q0 = 0.f, q1 = 0.f;
    for (int n = n0 + w; n < n1; n += 4) {
        float2 acc = make_float2(0.f, 0.f);
#pragma unroll
        for (int k = 0; k < 9; ++k) {
            float a = aggx[n * 16 + k];
            float2 wv = *(const float2*)&w0[k * HD + c];
            acc.x += a * wv.x;
            acc.y += a * wv.y;
        }
        half_t hx = (half_t)acc.x, hy = (half_t)acc.y;
        half2v hv = {hx, hy};
        *(half2v*)&gout[n * HD + c] = hv;
        float fx = (float)hx, fy = (float)hy;
        s0 += fx; q0 += fx * fx; s1 += fy; q1 += fy * fy;
    }
    lsum[w][c] = s0; lsum[w][c + 1] = s1;
    lsq[w][c] = q0;  lsq[w][c + 1] = q1;
    __syncthreads();
    if (t < 128) {
        ps[blockIdx.x * 128 + t] = lsum[0][t] + lsum[1][t] + lsum[2][t] + lsum[3][t];
        ps2[blockIdx.x * 128 + t] = lsq[0][t] + lsq[1][t] + lsq[2][t] + lsq[3][t];
    }
}

// one block per channel, tree-reduce nb partials
__global__ __launch_bounds__(256) void k_stats2(const float* __restrict__ ps,
        const float* __restrict__ ps2, const float* __restrict__ g,
        const float* __restrict__ be, float* __restrict__ scale,
        float* __restrict__ shift, int nb) {
    __shared__ float sa[256], sb[256];
    int c = blockIdx.x, t = threadIdx.x;
    float S = 0.f, Q = 0.f;
    for (int i = t; i < nb; i += 256) {
        S += ps[i * 128 + c];
        Q += ps2[i * 128 + c];
    }
    sa[t] = S; sb[t] = Q;
    __syncthreads();
    for (int o = 128; o; o >>= 1) {
        if (t < o) { sa[t] += sa[t + o]; sb[t] += sb[t + o]; }
        __syncthreads();
    }
    if (t == 0) {
        double mu = (double)sa[0] / NN;
        double var = (double)sb[0] / NN - mu * mu;
        float sc = g[c] * rsqrtf((float)var + EPSV);
        scale[c] = sc;
        shift[c] = be[c] - (float)mu * sc;
    }
}

// ---------------- MFMA matmul: hh = relu(bn(gf)) @ W · dinv, fp16 out ----------------

__global__ __launch_bounds__(256) void k_mm_mfma(const half_t* __restrict__ gf,
        const float* __restrict__ scale, const float* __restrict__ shift,
        const float* __restrict__ dinv, const half_t* __restrict__ Wt,
        half_t* __restrict__ hh) {
    __shared__ half_t wlds[16384];   // [n][k] fp16, 16B-XOR swizzled
    int t = threadIdx.x;
#pragma unroll
    for (int j = 0; j < 8; ++j) {
        int cidx = t * 8 + j;          // 16-B chunk
        int n = cidx >> 4, k8 = cidx & 15;
        half8 v = *(const half8*)&Wt[cidx * 8];
        int byte = n * 256 + ((k8 * 16) ^ ((n & 7) << 4));
        *(half8*)((char*)wlds + byte) = v;
    }
    __syncthreads();
    int w = t >> 6, l = t & 63;
    int lr = l & 15, lg = l >> 4;
    int base = (blockIdx.x * 4 + w) * 16;
    int row = base + lr;
    bool rowok = row < NN;
    f32x4 acc[8];
#pragma unroll
    for (int nt = 0; nt < 8; ++nt) acc[nt] = (f32x4){0.f, 0.f, 0.f, 0.f};
#pragma unroll
    for (int kk = 0; kk < 4; ++kk) {
        int ch0 = kk * 32 + lg * 8;
        half8 a8;
        if (rowok) {
            half8 hv = *(const half8*)&gf[row * HD + ch0];
            f32x4 sc0 = *(const f32x4*)&scale[ch0];
            f32x4 sc1 = *(const f32x4*)&scale[ch0 + 4];
            f32x4 sh0 = *(const f32x4*)&shift[ch0];
            f32x4 sh1 = *(const f32x4*)&shift[ch0 + 4];
#pragma unroll
            for (int i = 0; i < 4; ++i)
                a8[i] = (half_t)fmaxf((float)hv[i] * sc0[i] + sh0[i], 0.f);
#pragma unroll
            for (int i = 0; i < 4; ++i)
                a8[4 + i] = (half_t)fmaxf((float)hv[4 + i] * sc1[i] + sh1[i], 0.f);
        } else {
#pragma unroll
            for (int i = 0; i < 8; ++i) a8[i] = (half_t)0.f;
        }
        int kbyte = kk * 64 + lg * 16;
#pragma unroll
        for (int nt = 0; nt < 8; ++nt) {
            int n = nt * 16 + lr;
            half8 b8 = *(const half8*)((const char*)wlds + n * 256 + (kbyte ^ ((n & 7) << 4)));
            acc[nt] = __builtin_amdgcn_mfma_f32_16x16x32_f16(a8, b8, acc[nt], 0, 0, 0);
        }
    }
#pragma unroll
    for (int i = 0; i < 4; ++i) {
        int r = base + lg * 4 + i;
        if (r < NN) {
            float dv = dinv[r];
#pragma unroll
            for (int nt = 0; nt < 8; ++nt)
                hh[r * HD + nt * 16 + lr] = (half_t)(acc[nt][i] * dv);
        }
    }
}

// ---------------- fp16 CSR gather (16-lane sub-groups) + fused stats ----------------

__global__ __launch_bounds__(256) void k_agg_h(const half_t* __restrict__ hh,
        const float* __restrict__ dinv, half_t* __restrict__ gout,
        const int* __restrict__ rp, const int* __restrict__ col,
        float* __restrict__ ps, float* __restrict__ ps2) {
    __shared__ float lsum[16][128], lsq[16][128];
    int t = threadIdx.x, w = t >> 6, l = t & 63;
    int sub = l >> 4, li = l & 15;
    int sg = w * 4 + sub;             // 0..15
    int c0 = li * 8;
    int n0 = blockIdx.x * CH_AG;
    int n1 = min(NN, n0 + CH_AG);
    float sacc[8], qacc[8];
#pragma unroll
    for (int j = 0; j < 8; ++j) { sacc[j] = 0.f; qacc[j] = 0.f; }
    for (int n = n0 + sg; n < n1; n += 16) {
        int s = rp[n], e = rp[n + 1];
        float facc[8];
#pragma unroll
        for (int j = 0; j < 8; ++j) facc[j] = 0.f;
        int i = s;
        for (; i + 1 < e; i += 2) {
            int ca = col[i], cb = col[i + 1];
            half8 v0 = *(const half8*)&hh[ca * HD + c0];
            half8 v1 = *(const half8*)&hh[cb * HD + c0];
#pragma unroll
            for (int j = 0; j < 8; ++j) facc[j] += (float)v0[j] + (float)v1[j];
        }
        if (i < e) {
            half8 v0 = *(const half8*)&hh[col[i] * HD + c0];
#pragma unroll
            for (int j = 0; j < 8; ++j) facc[j] += (float)v0[j];
        }
        float dv = dinv[n];
        half8 hv;
#pragma unroll
        for (int j = 0; j < 8; ++j) hv[j] = (half_t)(facc[j] * dv);
        *(half8*)&gout[n * HD + c0] = hv;
#pragma unroll
        for (int j = 0; j < 8; ++j) {
            float f = (float)hv[j];
            sacc[j] += f;
            qacc[j] += f * f;
        }
    }
#pragma unroll
    for (int j = 0; j < 8; ++j) {
        lsum[sg][c0 + j] = sacc[j];
        lsq[sg][c0 + j] = qacc[j];
    }
    __syncthreads();
    if (t < 128) {
        float S = 0.f, Q = 0.f;
#pragma unroll
        for (int g = 0; g < 16; ++g) { S += lsum[g][t]; Q += lsq[g][t]; }
        ps[blockIdx.x * 128 + t] = S;
        ps2[blockIdx.x * 128 + t] = Q;
    }
}

// ---------------- pooling (fused final BN+ReLU) + MLP ----------------

__global__ void k_pool_fused(const half_t* __restrict__ h, const float* __restrict__ scale,
                             const float* __restrict__ shift, const int* __restrict__ batch,
                             float* __restrict__ xg) {
    int l = threadIdx.x & 63;
    int g = blockIdx.x * (blockDim.x >> 6) + (threadIdx.x >> 6);
    if (g >= NG) return;
    int c = 2 * l;
    float2 sc = make_float2(scale[c], scale[c + 1]);
    float2 sh = make_float2(shift[c], shift[c + 1]);
    int lo = 0, hi = NN;
    while (lo < hi) { int m = (lo + hi) >> 1; if (batch[m] < g) lo = m + 1; else hi = m; }
    int s = lo;
    hi = NN;
    while (lo < hi) { int m = (lo + hi) >> 1; if (batch[m] < g + 1) lo = m + 1; else hi = m; }
    int e = lo;
    float2 sum = make_float2(0.f, 0.f), mx = make_float2(-3e38f, -3e38f);
    for (int r = s; r < e; ++r) {
        half2v hv = *(const half2v*)&h[r * HD + c];
        float vx = fmaxf((float)hv[0] * sc.x + sh.x, 0.f);
        float vy = fmaxf((float)hv[1] * sc.y + sh.y, 0.f);
        sum.x += vx; sum.y += vy;
        mx.x = fmaxf(mx.x, vx); mx.y = fmaxf(mx.y, vy);
    }
    float2 mean = make_float2(0.f, 0.f), mxo = make_float2(0.f, 0.f);
    if (e > s) {
        float cnt = (float)(e - s);
        mean.x = sum.x / cnt; mean.y = sum.y / cnt;
        mxo = mx;
    }
    *(float2*)&xg[g * 256 + c] = mean;
    *(float2*)&xg[g * 256 + 128 + c] = mxo;
}

#define GPB 8
__global__ __launch_bounds__(256) void k_mlp(const float* __restrict__ xg,
                                             const float* __restrict__ m0w, const float* __restrict__ m0b,
                                             const float* __restrict__ m1w, const float* __restrict__ m1b,
                                             const float* __restrict__ m2w, const float* __restrict__ m2b,
                                             float* __restrict__ out) {
    __shared__ float xs[GPB][256];
    __shared__ float h1[GPB][256];
    __shared__ float h2[GPB][64];
    int t = threadIdx.x;
    int g0 = blockIdx.x * GPB;
#pragma unroll
    for (int j = 0; j < GPB; ++j) xs[j][t] = xg[(g0 + j) * 256 + t];
    __syncthreads();
    float acc[GPB];
#pragma unroll
    for (int j = 0; j < GPB; ++j) acc[j] = m0b[t];
    for (int i = 0; i < 256; ++i) {
        float wv = m0w[i * 256 + t];
#pragma unroll
        for (int j = 0; j < GPB; ++j) acc[j] += xs[j][i] * wv;
    }
#pragma unroll
    for (int j = 0; j < GPB; ++j) h1[j][t] = fmaxf(acc[j], 0.f);
    __syncthreads();
    if (t < 64) {
        float a2[GPB];
#pragma unroll
        for (int j = 0; j < GPB; ++j) a2[j] = m1b[t];
        for (int i = 0; i < 256; ++i) {
            float wv = m1w[i * 64 + t];
#pragma unroll
            for (int j = 0; j < GPB; ++j) a2[j] += h1[j][i] * wv;
        }
#pragma unroll
        for (int j = 0; j < GPB; ++j) h2[j][t] = fmaxf(a2[j], 0.f);
    }
    __syncthreads();
    if (t < 64) {
#pragma unroll
        for (int j = 0; j < GPB; ++j) {
            float v = h2[j][t] * m2w[t];
            for (int off = 32; off; off >>= 1) v += __shfl_down(v, off);
            if (t == 0) out[g0 + j] = v + m2b[0];
        }
    }
}

// ---------------- launch ----------------

extern "C" void kernel_launch(void* const* d_in, const int* in_sizes, int n_in,
                              void* d_out, int out_size, void* d_ws, size_t ws_size,
                              hipStream_t stream) {
    const float* x    = (const float*)d_in[0];
    const int*   ei   = (const int*)d_in[1];
    const int*   batch= (const int*)d_in[2];
    const float* w0   = (const float*)d_in[3];
    const float* w12  = (const float*)d_in[4];
    // d_in[5] = cb : cancelled by BN mean-subtraction
    const float* bn_g = (const float*)d_in[6];
    const float* bn_b = (const float*)d_in[7];
    const float* m0w  = (const float*)d_in[8];
    const float* m0b  = (const float*)d_in[9];
    const float* m1w  = (const float*)d_in[10];
    const float* m1b  = (const float*)d_in[11];
    const float* m2w  = (const float*)d_in[12];
    const float* m2b  = (const float*)d_in[13];
    float* out = (float*)d_out;

    char* p = (char*)d_ws;
    auto alloc = [&](size_t bytes) {
        void* r = (void*)p;
        p += (bytes + 255) & ~(size_t)255;
        return r;
    };
    half_t*   gf0    = (half_t*)alloc((size_t)NN * HD * 2);
    half_t*   gf1    = (half_t*)alloc((size_t)NN * HD * 2);
    half_t*   hh     = (half_t*)alloc((size_t)NN * HD * 2);
    half_t*   xh     = (half_t*)alloc((size_t)NN * 16 * 2);
    float*    aggx   = (float*)alloc((size_t)NN * 16 * 4);
    half_t*   Wt     = (half_t*)alloc((size_t)2 * 128 * 128 * 2);
    float*    dinv   = (float*)alloc((size_t)NN * 4);
    int*      rp     = (int*)alloc((size_t)(NN + 1) * 4);
    int*      col    = (int*)alloc((size_t)(NE + NN) * 4);
    unsigned* binned = (unsigned*)alloc((size_t)NE * 4);
    int*      bcnt   = (int*)alloc(512 * 4);
    int*      ebase  = (int*)alloc(512 * 4);
    int*      gcur   = (int*)alloc(512 * 4);
    float*    ps     = (float*)alloc((size_t)NB_AG * 128 * 4);
    float*    ps2    = (float*)alloc((size_t)NB_AG * 128 * 4);
    float*    scb    = (float*)alloc(3 * 128 * 4);
    float*    shb    = (float*)alloc(3 * 128 * 4);
    float*    xg     = (float*)alloc((size_t)NG * 256 * 4);

    // ---- CSR build ----
    k_zero_i32<<<2, 256, 0, stream>>>(bcnt, 512);
    k_bcount<<<NBIN_BLK, 256, 0, stream>>>(ei, bcnt);
    k_bscan<<<1, 512, 0, stream>>>(bcnt, ebase, gcur);
    k_bin<<<NBIN_BLK, 256, 0, stream>>>(ei, gcur, binned);
    k_csr<<<NBUCK, 256, 0, stream>>>(binned, ebase, rp, dinv, col);

    // ---- weight prep ----
    k_cvtw<<<128, 256, 0, stream>>>(w12, Wt);

    // ---- layer 0 ----
    k_padx<<<(NN + 255) / 256, 256, 0, stream>>>(x, dinv, xh);
    k_aggx<<<(NN * 4 + 255) / 256, 256, 0, stream>>>(xh, dinv, aggx, rp, col);
    k_mm9<<<NB_MM, 256, 0, stream>>>(aggx, w0, gf0, ps, ps2);
    k_stats2<<<128, 256, 0, stream>>>(ps, ps2, bn_g + 0, bn_b + 0, scb + 0, shb + 0, NB_MM);

    // ---- layer 1 ----
    k_mm_mfma<<<(NN + 63) / 64, 256, 0, stream>>>(gf0, scb + 0, shb + 0, dinv, Wt, hh);
    k_agg_h<<<NB_AG, 256, 0, stream>>>(hh, dinv, gf1, rp, col, ps, ps2);
    k_stats2<<<128, 256, 0, stream>>>(ps, ps2, bn_g + 128, bn_b + 128, scb + 128, shb + 128, NB_AG);

    // ---- layer 2 ----
    k_mm_mfma<<<(NN + 63) / 64, 256, 0, stream>>>(gf1, scb + 128, shb + 128, dinv, Wt + 16384, hh);
    k_agg_h<<<NB_AG, 256, 0, stream>>>(hh, dinv, gf0, rp, col, ps, ps2);
    k_stats2<<<128, 256, 0, stream>>>(ps, ps2, bn_g + 256, bn_b + 256, scb + 256, shb + 256, NB_AG);

    // ---- pool + MLP ----
    k_pool_fused<<<NG / 4, 256, 0, stream>>>(gf0, scb + 256, shb + 256, batch, xg);
    k_mlp<<<NG / GPB, 256, 0, stream>>>(xg, m0w, m0b, m1w, m1b, m2w, m2b, out);
}